// Round 1
// baseline (3244.965 us; speedup 1.0000x reference)
//
#include <hip/hip_runtime.h>
#include <math.h>

#define Nn  50000
#define En  800000
#define DIN 500
#define Hd  128
#define Cc  40
#define Bb  10000
#define Ll  9
#define KT  5

// ---------------- input GEMM: h = relu(x @ W1 + b1); x0 = h ----------------
__global__ __launch_bounds__(128) void k_in(const float* __restrict__ x,
    const float* __restrict__ W1, const float* __restrict__ b1,
    float* __restrict__ h, float* __restrict__ x0) {
  __shared__ float sx[16][DIN];
  const int tid = threadIdx.x;
  const int row0 = blockIdx.x * 16;
  for (int i = tid; i < 16 * DIN; i += 128) {
    int r = i / DIN, k = i - r * DIN;
    sx[r][k] = x[(size_t)(row0 + r) * DIN + k];
  }
  __syncthreads();
  float acc[16];
#pragma unroll
  for (int r = 0; r < 16; ++r) acc[r] = 0.f;
  const int j = tid;
  for (int k4 = 0; k4 < DIN / 4; ++k4) {
    const int k = k4 * 4;
    const float w0 = W1[(k + 0) * Hd + j];
    const float w1 = W1[(k + 1) * Hd + j];
    const float w2 = W1[(k + 2) * Hd + j];
    const float w3 = W1[(k + 3) * Hd + j];
#pragma unroll
    for (int r = 0; r < 16; ++r) {
      const float4 a = *(const float4*)&sx[r][k];
      acc[r] += a.x * w0 + a.y * w1 + a.z * w2 + a.w * w3;
    }
  }
  const float bb = b1[j];
#pragma unroll
  for (int r = 0; r < 16; ++r) {
    float v = fmaxf(acc[r] + bb, 0.f);
    int gi = (row0 + r) * Hd + j;
    h[gi] = v;
    x0[gi] = v;
  }
}

// ---------------- CSR build ----------------
__global__ void k_hist(const int* __restrict__ rows, int* __restrict__ counts) {
  int e = blockIdx.x * 256 + threadIdx.x;
  if (e < En) atomicAdd(&counts[rows[e]], 1);
}

__global__ __launch_bounds__(1024) void k_scan(const int* __restrict__ counts,
                                               int* __restrict__ ptr) {
  __shared__ int buf[1024];
  __shared__ int s_base;
  const int tid = threadIdx.x;
  if (tid == 0) { s_base = 0; ptr[0] = 0; }
  __syncthreads();
  for (int start = 0; start < Nn; start += 1024) {
    int i = start + tid;
    int v = (i < Nn) ? counts[i] : 0;
    buf[tid] = v;
    __syncthreads();
    for (int off = 1; off < 1024; off <<= 1) {
      int t = (tid >= off) ? buf[tid - off] : 0;
      __syncthreads();
      buf[tid] += t;
      __syncthreads();
    }
    if (i < Nn) ptr[i + 1] = s_base + buf[tid];
    __syncthreads();
    if (tid == 0) s_base += buf[1023];
    __syncthreads();
  }
}

__global__ void k_scatter(const int* __restrict__ rows, const int* __restrict__ cols,
                          const float* __restrict__ w, const int* __restrict__ ptr,
                          int* __restrict__ fill, int* __restrict__ csr_col,
                          float* __restrict__ csr_w) {
  int e = blockIdx.x * 256 + threadIdx.x;
  if (e >= En) return;
  int r = rows[e];
  int pos = atomicAdd(&fill[r], 1);
  int d = ptr[r] + pos;
  csr_col[d] = cols[e];
  csr_w[d] = w[e];
}

// ---------------- SpMM: p = 0.5 * segment_sum(w * h[col]) ----------------
__global__ __launch_bounds__(256) void k_spmm(const int* __restrict__ ptr,
    const int* __restrict__ csr_col, const float* __restrict__ csr_w,
    const float* __restrict__ h, float* __restrict__ p) {
  const int wave = (blockIdx.x * 256 + threadIdx.x) >> 6;
  const int lane = threadIdx.x & 63;
  if (wave >= Nn) return;
  const int s = ptr[wave], e_end = ptr[wave + 1];
  float a0 = 0.f, a1 = 0.f;
  for (int e = s; e < e_end; ++e) {
    const int c = csr_col[e];
    const float w = csr_w[e];
    const float* hc = h + (size_t)c * Hd;
    a0 += w * hc[lane];
    a1 += w * hc[lane + 64];
  }
  p[wave * Hd + lane] = 0.5f * a0;
  p[wave * Hd + lane + 64] = 0.5f * a1;
}

// ---------------- layer: h = relu(h + (1-b)(p + 0.5 x0) + b(p@W1l) + 0.5 b(x0@W2l))
__global__ __launch_bounds__(256) void k_layer(const float* __restrict__ p,
    const float* __restrict__ x0, float* __restrict__ h,
    const float* __restrict__ W1l, const float* __restrict__ W2l, float beta) {
  __shared__ float sp[16][Hd];
  __shared__ float sx[16][Hd];
  __shared__ float part1[16][Hd];
  __shared__ float part2[16][Hd];
  const int tid = threadIdx.x;
  const int j = tid & 127;
  const int half = tid >> 7;
  const int row0 = blockIdx.x * 16;
  for (int i = tid; i < 16 * Hd; i += 256) {
    int r = i >> 7, k = i & 127;
    sp[r][k] = p[(row0 + r) * Hd + k];
    sx[r][k] = x0[(row0 + r) * Hd + k];
  }
  __syncthreads();
  float acc1[16], acc2[16];
#pragma unroll
  for (int r = 0; r < 16; ++r) { acc1[r] = 0.f; acc2[r] = 0.f; }
  const int kbase = half * 64;
  for (int k4 = 0; k4 < 16; ++k4) {
    const int k = kbase + k4 * 4;
    const float w1a = W1l[(k + 0) * Hd + j];
    const float w1b = W1l[(k + 1) * Hd + j];
    const float w1c = W1l[(k + 2) * Hd + j];
    const float w1d = W1l[(k + 3) * Hd + j];
    const float w2a = W2l[(k + 0) * Hd + j];
    const float w2b = W2l[(k + 1) * Hd + j];
    const float w2c = W2l[(k + 2) * Hd + j];
    const float w2d = W2l[(k + 3) * Hd + j];
#pragma unroll
    for (int r = 0; r < 16; ++r) {
      const float4 a = *(const float4*)&sp[r][k];
      acc1[r] += a.x * w1a + a.y * w1b + a.z * w1c + a.w * w1d;
      const float4 b = *(const float4*)&sx[r][k];
      acc2[r] += b.x * w2a + b.y * w2b + b.z * w2c + b.w * w2d;
    }
  }
  __syncthreads();
  if (half == 1) {
#pragma unroll
    for (int r = 0; r < 16; ++r) { part1[r][j] = acc1[r]; part2[r][j] = acc2[r]; }
  }
  __syncthreads();
  if (half == 0) {
    const float om = 1.f - beta;
#pragma unroll
    for (int r = 0; r < 16; ++r) {
      const float g1 = acc1[r] + part1[r][j];   // p @ W1l
      const float g2 = acc2[r] + part2[r][j];   // x0 @ W2l
      const int gi = (row0 + r) * Hd + j;
      const float out = om * (sp[r][j] + 0.5f * sx[r][j]) + beta * g1 + 0.5f * beta * g2;
      h[gi] = fmaxf(h[gi] + out, 0.f);
    }
  }
}

// ---------------- head: emb, an = emb/||emb||, p_lc = log_softmax(h@W2+b2) ----
__global__ __launch_bounds__(256) void k_head(const float* __restrict__ h,
    const float* __restrict__ W2, const float* __restrict__ b2,
    float* __restrict__ an, float* __restrict__ p_lc, float* __restrict__ out_emb) {
  const int wid = (blockIdx.x * 256 + threadIdx.x) >> 6;
  const int lane = threadIdx.x & 63;
  if (wid >= Bb) return;
  const float* hr = h + (size_t)wid * Hd;
  const float v0 = hr[lane], v1 = hr[lane + 64];
  out_emb[wid * Hd + lane] = v0;
  out_emb[wid * Hd + lane + 64] = v1;
  float ss = v0 * v0 + v1 * v1;
#pragma unroll
  for (int off = 32; off > 0; off >>= 1) ss += __shfl_xor(ss, off);
  const float inv = 1.f / fmaxf(sqrtf(ss), 1e-8f);
  an[wid * Hd + lane] = v0 * inv;
  an[wid * Hd + lane + 64] = v1 * inv;
  float l = 0.f;
  if (lane < Cc) {
    for (int k = 0; k < Hd; ++k) l += hr[k] * W2[k * Cc + lane];
    l += b2[lane];
  }
  float lm = (lane < Cc) ? l : -3.0e38f;
#pragma unroll
  for (int off = 32; off > 0; off >>= 1) lm = fmaxf(lm, __shfl_xor(lm, off));
  float ex = (lane < Cc) ? expf(l - lm) : 0.f;
#pragma unroll
  for (int off = 32; off > 0; off >>= 1) ex += __shfl_xor(ex, off);
  const float lse = logf(ex);
  if (lane < Cc) p_lc[wid * Cc + lane] = l - lm - lse;
}

// ---------------- fused sim = an@an^T with running top-5 ----------------
// grid: (rowtiles=157) x (col halves=2). block 256 = 16x16 threads, 4x4 regs.
#define RT 64
#define CT 64
#define HB 5000
__global__ __launch_bounds__(256) void k_simtopk(const float* __restrict__ an,
    float* __restrict__ cval, int* __restrict__ cidx) {
  __shared__ float smem[2 * Hd * RT];  // sa [128][64] | sb [128][64]
  float* sa = smem;
  float* sb = smem + Hd * RT;
  const int rt = blockIdx.x >> 1;
  const int half = blockIdx.x & 1;
  const int row0 = rt * RT;
  const int col_begin = half * HB;
  const int col_end = col_begin + HB;
  const int tid = threadIdx.x;
  for (int i = tid; i < RT * Hd; i += 256) {
    int r = i >> 7, k = i & 127;
    int gr = row0 + r;
    sa[k * RT + r] = (gr < Bb) ? an[gr * Hd + k] : 0.f;
  }
  const int tr = tid >> 4, tc = tid & 15;
  float bv[4][KT];
  int bi[4][KT];
#pragma unroll
  for (int r = 0; r < 4; ++r)
#pragma unroll
    for (int t = 0; t < KT; ++t) { bv[r][t] = -3.0e38f; bi[r][t] = 0x7fffffff; }

  for (int ct = 0; ct < (HB + CT - 1) / CT; ++ct) {
    const int c0 = col_begin + ct * CT;
    __syncthreads();
    for (int i = tid; i < CT * Hd; i += 256) {
      int c = i >> 7, k = i & 127;
      int gc = c0 + c;
      sb[k * CT + c] = (gc < col_end) ? an[gc * Hd + k] : 0.f;
    }
    __syncthreads();
    float acc[4][4];
#pragma unroll
    for (int a = 0; a < 4; ++a)
#pragma unroll
      for (int b = 0; b < 4; ++b) acc[a][b] = 0.f;
    for (int k = 0; k < Hd; ++k) {
      const float4 a = *(const float4*)&sa[k * RT + tr * 4];
      const float4 b = *(const float4*)&sb[k * CT + tc * 4];
      acc[0][0] += a.x * b.x; acc[0][1] += a.x * b.y; acc[0][2] += a.x * b.z; acc[0][3] += a.x * b.w;
      acc[1][0] += a.y * b.x; acc[1][1] += a.y * b.y; acc[1][2] += a.y * b.z; acc[1][3] += a.y * b.w;
      acc[2][0] += a.z * b.x; acc[2][1] += a.z * b.y; acc[2][2] += a.z * b.z; acc[2][3] += a.z * b.w;
      acc[3][0] += a.w * b.x; acc[3][1] += a.w * b.y; acc[3][2] += a.w * b.z; acc[3][3] += a.w * b.w;
    }
#pragma unroll
    for (int ri = 0; ri < 4; ++ri) {
#pragma unroll
      for (int ci = 0; ci < 4; ++ci) {
        const int gc = c0 + tc * 4 + ci;
        const float v = (gc < col_end) ? acc[ri][ci] : -3.0e38f;
        if (v > bv[ri][KT - 1]) {   // ascending col order => lowest-index tie pref
          float tv = v; int ti = gc;
#pragma unroll
          for (int t = 0; t < KT; ++t) {
            if (tv > bv[ri][t]) {
              float ov = bv[ri][t]; int oi = bi[ri][t];
              bv[ri][t] = tv; bi[ri][t] = ti; tv = ov; ti = oi;
            }
          }
        }
      }
    }
  }
  // merge the 16 col-thread lists per row
  __syncthreads();
  float* mv = smem;                       // [64][80]
  int* mi = (int*)(smem + RT * 80);
#pragma unroll
  for (int ri = 0; ri < 4; ++ri)
#pragma unroll
    for (int t = 0; t < KT; ++t) {
      mv[(tr * 4 + ri) * 80 + tc * KT + t] = bv[ri][t];
      mi[(tr * 4 + ri) * 80 + tc * KT + t] = bi[ri][t];
    }
  __syncthreads();
  if (tid < RT) {
    const int gr = row0 + tid;
    if (gr < Bb) {
      float tv5[KT]; int ti5[KT];
#pragma unroll
      for (int t = 0; t < KT; ++t) { tv5[t] = -3.0e38f; ti5[t] = 0x7fffffff; }
      for (int m = 0; m < 80; ++m) {
        float v = mv[tid * 80 + m]; int id = mi[tid * 80 + m];
        if (v > tv5[KT - 1] || (v == tv5[KT - 1] && id < ti5[KT - 1])) {
#pragma unroll
          for (int t = 0; t < KT; ++t) {
            if (v > tv5[t] || (v == tv5[t] && id < ti5[t])) {
              float ov = tv5[t]; int oi = ti5[t];
              tv5[t] = v; ti5[t] = id; v = ov; id = oi;
            }
          }
        }
      }
#pragma unroll
      for (int t = 0; t < KT; ++t) {
        cval[gr * 10 + half * KT + t] = tv5[t];
        cidx[gr * 10 + half * KT + t] = ti5[t];
      }
    }
  }
}

// ---------------- final: merge halves, fused one-hot, log_softmax, combine ----
__global__ __launch_bounds__(256) void k_final(const float* __restrict__ cval,
    const int* __restrict__ cidx, const int* __restrict__ y,
    const float* __restrict__ p_lc, float* __restrict__ out_final) {
  const int b = blockIdx.x * 256 + threadIdx.x;
  if (b >= Bb) return;
  float tv5[KT]; int ti5[KT];
#pragma unroll
  for (int t = 0; t < KT; ++t) { tv5[t] = -3.0e38f; ti5[t] = 0x7fffffff; }
#pragma unroll
  for (int m = 0; m < 10; ++m) {
    float v = cval[b * 10 + m]; int id = cidx[b * 10 + m];
    if (v > tv5[KT - 1] || (v == tv5[KT - 1] && id < ti5[KT - 1])) {
#pragma unroll
      for (int t = 0; t < KT; ++t) {
        if (v > tv5[t] || (v == tv5[t] && id < ti5[t])) {
          float ov = tv5[t]; int oi = ti5[t];
          tv5[t] = v; ti5[t] = id; v = ov; id = oi;
        }
      }
    }
  }
  float w[KT]; int cls[KT];
#pragma unroll
  for (int t = 0; t < KT; ++t) { w[t] = expf(tv5[t]); cls[t] = y[ti5[t]]; }
  float m = -3.0e38f;
  for (int c = 0; c < Cc; ++c) {
    float f = 0.f;
#pragma unroll
    for (int t = 0; t < KT; ++t) f += (cls[t] == c) ? w[t] : 0.f;
    m = fmaxf(m, f);
  }
  float s = 0.f;
  for (int c = 0; c < Cc; ++c) {
    float f = 0.f;
#pragma unroll
    for (int t = 0; t < KT; ++t) f += (cls[t] == c) ? w[t] : 0.f;
    s += expf(f - m);
  }
  const float lse = logf(s);
  for (int c = 0; c < Cc; ++c) {
    float f = 0.f;
#pragma unroll
    for (int t = 0; t < KT; ++t) f += (cls[t] == c) ? w[t] : 0.f;
    out_final[b * Cc + c] = 0.5f * p_lc[b * Cc + c] + 0.5f * (f - m - lse);
  }
}

extern "C" void kernel_launch(void* const* d_in, const int* in_sizes, int n_in,
                              void* d_out, int out_size, void* d_ws, size_t ws_size,
                              hipStream_t stream) {
  const float* x  = (const float*)d_in[0];
  const int* erow = (const int*)d_in[1];
  const int* ecol = erow + En;
  const float* ew = (const float*)d_in[2];
  const int* y    = (const int*)d_in[3];
  const float* W1 = (const float*)d_in[5];
  const float* b1 = (const float*)d_in[6];
  const float* cw1 = (const float*)d_in[7];
  const float* cw2 = (const float*)d_in[8];
  const float* W2 = (const float*)d_in[9];
  const float* b2 = (const float*)d_in[10];
  float* out = (float*)d_out;

  float* ws = (float*)d_ws;
  size_t off = 0;
  float* h   = ws + off; off += (size_t)Nn * Hd;
  float* x0  = ws + off; off += (size_t)Nn * Hd;
  float* p   = ws + off; off += (size_t)Nn * Hd;
  float* an  = ws + off; off += (size_t)Bb * Hd;
  float* plc = ws + off; off += (size_t)Bb * Cc;
  float* cval = ws + off; off += (size_t)Bb * 10;
  int* cidx  = (int*)(ws + off); off += (size_t)Bb * 10;
  int* counts = (int*)(ws + off); off += Nn;
  int* fill   = (int*)(ws + off); off += Nn;
  int* rptr   = (int*)(ws + off); off += Nn + 1;
  int* ccol   = (int*)(ws + off); off += En;
  float* cwt  = ws + off; off += En;

  k_in<<<Nn / 16, 128, 0, stream>>>(x, W1, b1, h, x0);
  hipMemsetAsync(counts, 0, (size_t)2 * Nn * sizeof(int), stream);
  k_hist<<<(En + 255) / 256, 256, 0, stream>>>(erow, counts);
  k_scan<<<1, 1024, 0, stream>>>(counts, rptr);
  k_scatter<<<(En + 255) / 256, 256, 0, stream>>>(erow, ecol, ew, rptr, fill, ccol, cwt);
  for (int l = 0; l < Ll; ++l) {
    const float beta = logf(1.0f / (float)(l + 1) + 1.0f);
    k_spmm<<<(Nn * 64 + 255) / 256, 256, 0, stream>>>(rptr, ccol, cwt, h, p);
    k_layer<<<Nn / 16, 256, 0, stream>>>(p, x0, h, cw1 + (size_t)l * Hd * Hd,
                                         cw2 + (size_t)l * Hd * Hd, beta);
  }
  k_head<<<(Bb * 64) / 256, 256, 0, stream>>>(h, W2, b2, an, plc, out + (size_t)Bb * Cc);
  k_simtopk<<<((Bb + RT - 1) / RT) * 2, 256, 0, stream>>>(an, cval, cidx);
  k_final<<<(Bb + 255) / 256, 256, 0, stream>>>(cval, cidx, y, plc, out);
}

// Round 2
// 2213.267 us; speedup vs baseline: 1.4661x; 1.4661x over previous
//
#include <hip/hip_runtime.h>
#include <hip/hip_bf16.h>
#include <math.h>

#define Nn  50000
#define En  800000
#define DIN 500
#define Hd  128
#define Cc  40
#define Bb  10000
#define Ll  9
#define KT  5

typedef short bf16x8 __attribute__((ext_vector_type(8)));
typedef float f32x4 __attribute__((ext_vector_type(4)));

// ---------------- input GEMM: h = relu(x @ W1 + b1); x0 = h ----------------
__global__ __launch_bounds__(128) void k_in(const float* __restrict__ x,
    const float* __restrict__ W1, const float* __restrict__ b1,
    float* __restrict__ h, float* __restrict__ x0) {
  __shared__ float sx[16][DIN];
  const int tid = threadIdx.x;
  const int row0 = blockIdx.x * 16;
  for (int i = tid; i < 16 * DIN; i += 128) {
    int r = i / DIN, k = i - r * DIN;
    sx[r][k] = x[(size_t)(row0 + r) * DIN + k];
  }
  __syncthreads();
  float acc[16];
#pragma unroll
  for (int r = 0; r < 16; ++r) acc[r] = 0.f;
  const int j = tid;
  for (int k4 = 0; k4 < DIN / 4; ++k4) {
    const int k = k4 * 4;
    const float w0 = W1[(k + 0) * Hd + j];
    const float w1 = W1[(k + 1) * Hd + j];
    const float w2 = W1[(k + 2) * Hd + j];
    const float w3 = W1[(k + 3) * Hd + j];
#pragma unroll
    for (int r = 0; r < 16; ++r) {
      const float4 a = *(const float4*)&sx[r][k];
      acc[r] += a.x * w0 + a.y * w1 + a.z * w2 + a.w * w3;
    }
  }
  const float bb = b1[j];
#pragma unroll
  for (int r = 0; r < 16; ++r) {
    float v = fmaxf(acc[r] + bb, 0.f);
    int gi = (row0 + r) * Hd + j;
    h[gi] = v;
    x0[gi] = v;
  }
}

// ---------------- CSR build ----------------
__global__ void k_hist(const int* __restrict__ rows, int* __restrict__ counts) {
  int e = blockIdx.x * 256 + threadIdx.x;
  if (e < En) atomicAdd(&counts[rows[e]], 1);
}

__global__ __launch_bounds__(1024) void k_scan(const int* __restrict__ counts,
                                               int* __restrict__ ptr) {
  __shared__ int buf[1024];
  __shared__ int s_base;
  const int tid = threadIdx.x;
  if (tid == 0) { s_base = 0; ptr[0] = 0; }
  __syncthreads();
  for (int start = 0; start < Nn; start += 1024) {
    int i = start + tid;
    int v = (i < Nn) ? counts[i] : 0;
    buf[tid] = v;
    __syncthreads();
    for (int off = 1; off < 1024; off <<= 1) {
      int t = (tid >= off) ? buf[tid - off] : 0;
      __syncthreads();
      buf[tid] += t;
      __syncthreads();
    }
    if (i < Nn) ptr[i + 1] = s_base + buf[tid];
    __syncthreads();
    if (tid == 0) s_base += buf[1023];
    __syncthreads();
  }
}

__global__ void k_scatter(const int* __restrict__ rows, const int* __restrict__ cols,
                          const float* __restrict__ w, const int* __restrict__ ptr,
                          int* __restrict__ fill, int* __restrict__ csr_col,
                          float* __restrict__ csr_w) {
  int e = blockIdx.x * 256 + threadIdx.x;
  if (e >= En) return;
  int r = rows[e];
  int pos = atomicAdd(&fill[r], 1);
  int d = ptr[r] + pos;
  csr_col[d] = cols[e];
  csr_w[d] = w[e];
}

// ---------------- SpMM: p = 0.5 * segment_sum(w * h[col]) ----------------
__global__ __launch_bounds__(256) void k_spmm(const int* __restrict__ ptr,
    const int* __restrict__ csr_col, const float* __restrict__ csr_w,
    const float* __restrict__ h, float* __restrict__ p) {
  const int wave = (blockIdx.x * 256 + threadIdx.x) >> 6;
  const int lane = threadIdx.x & 63;
  if (wave >= Nn) return;
  const int s = ptr[wave], e_end = ptr[wave + 1];
  float a0 = 0.f, a1 = 0.f;
  for (int e = s; e < e_end; ++e) {
    const int c = csr_col[e];
    const float w = csr_w[e];
    const float* hc = h + (size_t)c * Hd;
    a0 += w * hc[lane];
    a1 += w * hc[lane + 64];
  }
  p[wave * Hd + lane] = 0.5f * a0;
  p[wave * Hd + lane + 64] = 0.5f * a1;
}

// ---------------- layer: h = relu(h + (1-b)(p + 0.5 x0) + b(p@W1l) + 0.5 b(x0@W2l))
__global__ __launch_bounds__(256) void k_layer(const float* __restrict__ p,
    const float* __restrict__ x0, float* __restrict__ h,
    const float* __restrict__ W1l, const float* __restrict__ W2l, float beta) {
  __shared__ float sp[16][Hd];
  __shared__ float sx[16][Hd];
  __shared__ float part1[16][Hd];
  __shared__ float part2[16][Hd];
  const int tid = threadIdx.x;
  const int j = tid & 127;
  const int half = tid >> 7;
  const int row0 = blockIdx.x * 16;
  for (int i = tid; i < 16 * Hd; i += 256) {
    int r = i >> 7, k = i & 127;
    sp[r][k] = p[(row0 + r) * Hd + k];
    sx[r][k] = x0[(row0 + r) * Hd + k];
  }
  __syncthreads();
  float acc1[16], acc2[16];
#pragma unroll
  for (int r = 0; r < 16; ++r) { acc1[r] = 0.f; acc2[r] = 0.f; }
  const int kbase = half * 64;
  for (int k4 = 0; k4 < 16; ++k4) {
    const int k = kbase + k4 * 4;
    const float w1a = W1l[(k + 0) * Hd + j];
    const float w1b = W1l[(k + 1) * Hd + j];
    const float w1c = W1l[(k + 2) * Hd + j];
    const float w1d = W1l[(k + 3) * Hd + j];
    const float w2a = W2l[(k + 0) * Hd + j];
    const float w2b = W2l[(k + 1) * Hd + j];
    const float w2c = W2l[(k + 2) * Hd + j];
    const float w2d = W2l[(k + 3) * Hd + j];
#pragma unroll
    for (int r = 0; r < 16; ++r) {
      const float4 a = *(const float4*)&sp[r][k];
      acc1[r] += a.x * w1a + a.y * w1b + a.z * w1c + a.w * w1d;
      const float4 b = *(const float4*)&sx[r][k];
      acc2[r] += b.x * w2a + b.y * w2b + b.z * w2c + b.w * w2d;
    }
  }
  __syncthreads();
  if (half == 1) {
#pragma unroll
    for (int r = 0; r < 16; ++r) { part1[r][j] = acc1[r]; part2[r][j] = acc2[r]; }
  }
  __syncthreads();
  if (half == 0) {
    const float om = 1.f - beta;
#pragma unroll
    for (int r = 0; r < 16; ++r) {
      const float g1 = acc1[r] + part1[r][j];   // p @ W1l
      const float g2 = acc2[r] + part2[r][j];   // x0 @ W2l
      const int gi = (row0 + r) * Hd + j;
      const float out = om * (sp[r][j] + 0.5f * sx[r][j]) + beta * g1 + 0.5f * beta * g2;
      h[gi] = fmaxf(h[gi] + out, 0.f);
    }
  }
}

// ---------------- head: emb, an_bf16 = emb/||emb||, p_lc = log_softmax(h@W2+b2) ----
__global__ __launch_bounds__(256) void k_head(const float* __restrict__ h,
    const float* __restrict__ W2, const float* __restrict__ b2,
    unsigned short* __restrict__ anb, float* __restrict__ p_lc,
    float* __restrict__ out_emb) {
  const int wid = (blockIdx.x * 256 + threadIdx.x) >> 6;
  const int lane = threadIdx.x & 63;
  if (wid >= Bb) return;
  const float* hr = h + (size_t)wid * Hd;
  const float v0 = hr[lane], v1 = hr[lane + 64];
  out_emb[wid * Hd + lane] = v0;
  out_emb[wid * Hd + lane + 64] = v1;
  float ss = v0 * v0 + v1 * v1;
#pragma unroll
  for (int off = 32; off > 0; off >>= 1) ss += __shfl_xor(ss, off);
  const float inv = 1.f / fmaxf(sqrtf(ss), 1e-8f);
  __hip_bfloat16 b0 = __float2bfloat16(v0 * inv);
  __hip_bfloat16 b1v = __float2bfloat16(v1 * inv);
  anb[wid * Hd + lane] = *(unsigned short*)&b0;
  anb[wid * Hd + lane + 64] = *(unsigned short*)&b1v;
  float l = 0.f;
  if (lane < Cc) {
    for (int k = 0; k < Hd; ++k) l += hr[k] * W2[k * Cc + lane];
    l += b2[lane];
  }
  float lm = (lane < Cc) ? l : -3.0e38f;
#pragma unroll
  for (int off = 32; off > 0; off >>= 1) lm = fmaxf(lm, __shfl_xor(lm, off));
  float ex = (lane < Cc) ? expf(l - lm) : 0.f;
#pragma unroll
  for (int off = 32; off > 0; off >>= 1) ex += __shfl_xor(ex, off);
  const float lse = logf(ex);
  if (lane < Cc) p_lc[wid * Cc + lane] = l - lm - lse;
}

// ---------------- fused sim = an@an^T (bf16 MFMA) with running top-5 ----------
// grid = 157 row-tiles x 4 col chunks. block 256 = 4 waves x 16 rows.
#define CH_N  4
#define CH_SZ 2500
#define SB_LD 136   // 128 + 8 bf16 pad -> <=2-way LDS bank aliasing on b128 reads
__global__ __launch_bounds__(256) void k_simtopk(const unsigned short* __restrict__ anb,
    float* __restrict__ cval, int* __restrict__ cidx) {
  __shared__ __align__(16) char smem[40960];
  unsigned short* sb = (unsigned short*)smem;   // staged col tile [64][SB_LD]
  const int rt = blockIdx.x / CH_N;
  const int chunk = blockIdx.x % CH_N;
  const int row0 = rt * 64;
  const int cbeg = chunk * CH_SZ;
  const int cend = cbeg + CH_SZ;
  const int tid = threadIdx.x;
  const int wv = tid >> 6;
  const int lane = tid & 63;
  const int lrow = lane & 15;       // A-frag row / C col
  const int quad = lane >> 4;

  // A fragments: an[row0 + wv*16 + lrow][k], k = quad*8 + kq*32 + j
  union Frag { uint4 u4; bf16x8 v; };
  bf16x8 afr[4];
  const int ar = row0 + wv * 16 + lrow;
#pragma unroll
  for (int kq = 0; kq < 4; ++kq) {
    Frag f;
    f.u4 = make_uint4(0u, 0u, 0u, 0u);
    if (ar < Bb) f.u4 = *(const uint4*)(anb + (size_t)ar * Hd + kq * 32 + quad * 8);
    afr[kq] = f.v;
  }

  float bv[4][KT];
  int bi[4][KT];
#pragma unroll
  for (int r = 0; r < 4; ++r)
#pragma unroll
    for (int t = 0; t < KT; ++t) { bv[r][t] = -3.0e38f; bi[r][t] = 0x7fffffff; }

  const int ntile = (CH_SZ + 63) / 64;  // 40
  for (int t = 0; t < ntile; ++t) {
    const int c0 = cbeg + t * 64;
    __syncthreads();
    for (int i = tid; i < 1024; i += 256) {       // 64 cols x 16 uint4
      const int r = i >> 4, ch = i & 15;
      const int gc = c0 + r;
      uint4 v = make_uint4(0u, 0u, 0u, 0u);
      if (gc < cend) v = *(const uint4*)(anb + (size_t)gc * Hd + ch * 8);
      *(uint4*)&sb[r * SB_LD + ch * 8] = v;
    }
    __syncthreads();
#pragma unroll
    for (int sub = 0; sub < 4; ++sub) {
      f32x4 acc = {0.f, 0.f, 0.f, 0.f};
      const int scol = sub * 16 + lrow;
#pragma unroll
      for (int kq = 0; kq < 4; ++kq) {
        bf16x8 bfr = *(const bf16x8*)&sb[scol * SB_LD + kq * 32 + quad * 8];
        acc = __builtin_amdgcn_mfma_f32_16x16x32_bf16(afr[kq], bfr, acc, 0, 0, 0);
      }
      const int gc = c0 + scol;
      const bool ok = gc < cend;
#pragma unroll
      for (int i = 0; i < 4; ++i) {
        const float v = ok ? acc[i] : -3.0e38f;
        if (v > bv[i][KT - 1]) {      // ascending col order => lowest-index tie pref
          float tv = v; int ti = gc;
#pragma unroll
          for (int s = 0; s < KT; ++s) {
            if (tv > bv[i][s]) {
              float ov = bv[i][s]; int oi = bi[i][s];
              bv[i][s] = tv; bi[i][s] = ti; tv = ov; ti = oi;
            }
          }
        }
      }
    }
  }

  // merge: 16 lanes (lrow) hold per-row top-5 lists for row wv*16 + quad*4 + i
  __syncthreads();
  float* mv = (float*)smem;                  // [64][80]
  int* mi = (int*)(smem + 20480);
#pragma unroll
  for (int i = 0; i < 4; ++i) {
    const int row = wv * 16 + quad * 4 + i;
#pragma unroll
    for (int t = 0; t < KT; ++t) {
      mv[row * 80 + lrow * KT + t] = bv[i][t];
      mi[row * 80 + lrow * KT + t] = bi[i][t];
    }
  }
  __syncthreads();
  if (tid < 64) {
    const int gr = row0 + tid;
    if (gr < Bb) {
      float tv5[KT]; int ti5[KT];
#pragma unroll
      for (int t = 0; t < KT; ++t) { tv5[t] = -3.0e38f; ti5[t] = 0x7fffffff; }
      for (int m = 0; m < 80; ++m) {
        float v = mv[tid * 80 + m]; int id = mi[tid * 80 + m];
        if (v > tv5[KT - 1] || (v == tv5[KT - 1] && id < ti5[KT - 1])) {
#pragma unroll
          for (int s = 0; s < KT; ++s) {
            if (v > tv5[s] || (v == tv5[s] && id < ti5[s])) {
              float ov = tv5[s]; int oi = ti5[s];
              tv5[s] = v; ti5[s] = id; v = ov; id = oi;
            }
          }
        }
      }
#pragma unroll
      for (int t = 0; t < KT; ++t) {
        cval[gr * (CH_N * KT) + chunk * KT + t] = tv5[t];
        cidx[gr * (CH_N * KT) + chunk * KT + t] = ti5[t];
      }
    }
  }
}

// ---------------- final: merge chunks, fused one-hot, log_softmax, combine ----
__global__ __launch_bounds__(256) void k_final(const float* __restrict__ cval,
    const int* __restrict__ cidx, const int* __restrict__ y,
    const float* __restrict__ p_lc, float* __restrict__ out_final) {
  const int b = blockIdx.x * 256 + threadIdx.x;
  if (b >= Bb) return;
  float tv5[KT]; int ti5[KT];
#pragma unroll
  for (int t = 0; t < KT; ++t) { tv5[t] = -3.0e38f; ti5[t] = 0x7fffffff; }
#pragma unroll
  for (int m = 0; m < CH_N * KT; ++m) {
    float v = cval[b * (CH_N * KT) + m]; int id = cidx[b * (CH_N * KT) + m];
    if (v > tv5[KT - 1] || (v == tv5[KT - 1] && id < ti5[KT - 1])) {
#pragma unroll
      for (int t = 0; t < KT; ++t) {
        if (v > tv5[t] || (v == tv5[t] && id < ti5[t])) {
          float ov = tv5[t]; int oi = ti5[t];
          tv5[t] = v; ti5[t] = id; v = ov; id = oi;
        }
      }
    }
  }
  float w[KT]; int cls[KT];
#pragma unroll
  for (int t = 0; t < KT; ++t) { w[t] = expf(tv5[t]); cls[t] = y[ti5[t]]; }
  float m = -3.0e38f;
  for (int c = 0; c < Cc; ++c) {
    float f = 0.f;
#pragma unroll
    for (int t = 0; t < KT; ++t) f += (cls[t] == c) ? w[t] : 0.f;
    m = fmaxf(m, f);
  }
  float s = 0.f;
  for (int c = 0; c < Cc; ++c) {
    float f = 0.f;
#pragma unroll
    for (int t = 0; t < KT; ++t) f += (cls[t] == c) ? w[t] : 0.f;
    s += expf(f - m);
  }
  const float lse = logf(s);
  for (int c = 0; c < Cc; ++c) {
    float f = 0.f;
#pragma unroll
    for (int t = 0; t < KT; ++t) f += (cls[t] == c) ? w[t] : 0.f;
    out_final[b * Cc + c] = 0.5f * p_lc[b * Cc + c] + 0.5f * (f - m - lse);
  }
}

extern "C" void kernel_launch(void* const* d_in, const int* in_sizes, int n_in,
                              void* d_out, int out_size, void* d_ws, size_t ws_size,
                              hipStream_t stream) {
  const float* x  = (const float*)d_in[0];
  const int* erow = (const int*)d_in[1];
  const int* ecol = erow + En;
  const float* ew = (const float*)d_in[2];
  const int* y    = (const int*)d_in[3];
  const float* W1 = (const float*)d_in[5];
  const float* b1 = (const float*)d_in[6];
  const float* cw1 = (const float*)d_in[7];
  const float* cw2 = (const float*)d_in[8];
  const float* W2 = (const float*)d_in[9];
  const float* b2 = (const float*)d_in[10];
  float* out = (float*)d_out;

  float* ws = (float*)d_ws;
  size_t off = 0;
  float* h   = ws + off; off += (size_t)Nn * Hd;
  float* x0  = ws + off; off += (size_t)Nn * Hd;
  float* p   = ws + off; off += (size_t)Nn * Hd;
  float* plc = ws + off; off += (size_t)Bb * Cc;
  float* cval = ws + off; off += (size_t)Bb * (CH_N * KT);
  int* cidx  = (int*)(ws + off); off += (size_t)Bb * (CH_N * KT);
  int* counts = (int*)(ws + off); off += Nn;
  int* fill   = (int*)(ws + off); off += Nn;
  int* rptr   = (int*)(ws + off); off += Nn + 4;   // +4 keeps later ptrs 16B-aligned
  int* ccol   = (int*)(ws + off); off += En;
  float* cwt  = ws + off; off += En;
  unsigned short* anb = (unsigned short*)(ws + off); off += (size_t)Bb * Hd / 2;

  k_in<<<Nn / 16, 128, 0, stream>>>(x, W1, b1, h, x0);
  hipMemsetAsync(counts, 0, (size_t)2 * Nn * sizeof(int), stream);
  k_hist<<<(En + 255) / 256, 256, 0, stream>>>(erow, counts);
  k_scan<<<1, 1024, 0, stream>>>(counts, rptr);
  k_scatter<<<(En + 255) / 256, 256, 0, stream>>>(erow, ecol, ew, rptr, fill, ccol, cwt);
  for (int l = 0; l < Ll; ++l) {
    const float beta = logf(1.0f / (float)(l + 1) + 1.0f);
    k_spmm<<<(Nn * 64 + 255) / 256, 256, 0, stream>>>(rptr, ccol, cwt, h, p);
    k_layer<<<Nn / 16, 256, 0, stream>>>(p, x0, h, cw1 + (size_t)l * Hd * Hd,
                                         cw2 + (size_t)l * Hd * Hd, beta);
  }
  k_head<<<(Bb * 64) / 256, 256, 0, stream>>>(h, W2, b2, anb, plc, out + (size_t)Bb * Cc);
  k_simtopk<<<((Bb + 63) / 64) * CH_N, 256, 0, stream>>>(anb, cval, cidx);
  k_final<<<(Bb + 255) / 256, 256, 0, stream>>>(cval, cidx, y, plc, out);
}

// Round 3
// 1596.773 us; speedup vs baseline: 2.0322x; 1.3861x over previous
//
#include <hip/hip_runtime.h>
#include <hip/hip_bf16.h>
#include <math.h>

#define Nn  50000
#define NR  50048   // rows padded to 64
#define En  800000
#define DIN 500
#define Hd  128
#define Cc  40
#define Bb  10000
#define Ll  9
#define KT  5

typedef short bf16x8 __attribute__((ext_vector_type(8)));
typedef unsigned short u16x8 __attribute__((ext_vector_type(8)));
typedef float f32x4 __attribute__((ext_vector_type(4)));

__device__ inline float bf2f(unsigned short u) {
  union { unsigned int i; float f; } c; c.i = (unsigned int)u << 16; return c.f;
}
__device__ inline unsigned short f2bf(float f) {
  __hip_bfloat16 b = __float2bfloat16(f);
  return *(unsigned short*)&b;
}

// ---------------- weight packing into B-fragment layout ----------------
// frag element j at [kk][quad][col]: B[k = kk*32 + quad*8 + j][col]
__global__ __launch_bounds__(256) void k_pack_w1(const float* __restrict__ W1,
                                                 unsigned short* __restrict__ W1p) {
  const int id = blockIdx.x * 256 + threadIdx.x;   // 16*4*128*8 = 65536
  if (id >= 65536) return;
  const int j = id & 7, col = (id >> 3) & 127, qk = id >> 10;  // qk = kk*4+quad
  const int k = (qk >> 2) * 32 + (qk & 3) * 8 + j;
  W1p[id] = f2bf((k < DIN) ? W1[(size_t)k * Hd + col] : 0.f);
}

// Wcat[l] = [W1l ; 0.5*W2l]  (K=256), same frag packing, 32768 elems/layer
__global__ __launch_bounds__(256) void k_pack_wc(const float* __restrict__ cw1,
    const float* __restrict__ cw2, unsigned short* __restrict__ Wcp) {
  const int id = blockIdx.x * 256 + threadIdx.x;   // 9*32768 = 294912
  if (id >= 294912) return;
  const int j = id & 7, col = (id >> 3) & 127, qk = (id >> 10) & 31, l = id >> 15;
  const int k = (qk >> 2) * 32 + (qk & 3) * 8 + j;  // 0..255
  float v;
  if (k < 128) v = cw1[((size_t)l * 128 + k) * 128 + col];
  else         v = 0.5f * cw2[((size_t)l * 128 + (k - 128)) * 128 + col];
  Wcp[id] = f2bf(v);
}

// ---------------- input GEMM (MFMA): h = relu(x @ W1 + b1) ----------------
// block 256 = 4 waves x 16 rows = 64 rows; N=128 (8 n-tiles); K=512 (16 steps)
__global__ __launch_bounds__(256) void k_in(const float* __restrict__ x,
    const unsigned short* __restrict__ W1p, const float* __restrict__ b1,
    float* __restrict__ h, unsigned short* __restrict__ hb,
    unsigned short* __restrict__ x0b) {
  const int tid = threadIdx.x;
  const int wv = tid >> 6, lane = tid & 63;
  const int lrow = lane & 15, quad = lane >> 4;
  const int row0 = blockIdx.x * 64;
  const int ar = row0 + wv * 16 + lrow;
  f32x4 acc[8];
#pragma unroll
  for (int t = 0; t < 8; ++t) acc[t] = (f32x4){0.f, 0.f, 0.f, 0.f};

  for (int kk = 0; kk < 16; ++kk) {
    const int kbase = kk * 32 + quad * 8;
    float av[8];
    if (ar < Nn) {
      if (kk < 15) {
        const float4 p0 = *(const float4*)(x + (size_t)ar * DIN + kbase);
        const float4 p1 = *(const float4*)(x + (size_t)ar * DIN + kbase + 4);
        av[0] = p0.x; av[1] = p0.y; av[2] = p0.z; av[3] = p0.w;
        av[4] = p1.x; av[5] = p1.y; av[6] = p1.z; av[7] = p1.w;
      } else {
#pragma unroll
        for (int j = 0; j < 8; ++j)
          av[j] = (kbase + j < DIN) ? x[(size_t)ar * DIN + kbase + j] : 0.f;
      }
    } else {
#pragma unroll
      for (int j = 0; j < 8; ++j) av[j] = 0.f;
    }
    bf16x8 af;
#pragma unroll
    for (int j = 0; j < 8; ++j) af[j] = (short)f2bf(av[j]);
#pragma unroll
    for (int nt = 0; nt < 8; ++nt) {
      const bf16x8 bf = *(const bf16x8*)(W1p + ((size_t)(kk * 4 + quad) * 128 + nt * 16 + lrow) * 8);
      acc[nt] = __builtin_amdgcn_mfma_f32_16x16x32_bf16(af, bf, acc[nt], 0, 0, 0);
    }
  }

  __shared__ float sacc[64 * 132];
#pragma unroll
  for (int nt = 0; nt < 8; ++nt)
#pragma unroll
    for (int i = 0; i < 4; ++i)
      sacc[(wv * 16 + quad * 4 + i) * 132 + nt * 16 + lrow] = acc[nt][i];
  __syncthreads();

  const int row = tid >> 2, cs = (tid & 3) * 32;
  const int gr = row0 + row;
  if (gr < Nn) {
#pragma unroll
    for (int g = 0; g < 4; ++g) {
      const int c0 = cs + g * 8;
      float v[8];
#pragma unroll
      for (int j = 0; j < 8; ++j)
        v[j] = fmaxf(sacc[row * 132 + c0 + j] + b1[c0 + j], 0.f);
      float4 o0 = {v[0], v[1], v[2], v[3]}, o1 = {v[4], v[5], v[6], v[7]};
      *(float4*)(h + (size_t)gr * Hd + c0) = o0;
      *(float4*)(h + (size_t)gr * Hd + c0 + 4) = o1;
      u16x8 ob;
#pragma unroll
      for (int j = 0; j < 8; ++j) ob[j] = f2bf(v[j]);
      *(u16x8*)(hb + (size_t)gr * Hd + c0) = ob;
      *(u16x8*)(x0b + (size_t)gr * Hd + c0) = ob;
    }
  }
}

// ---------------- CSR build ----------------
__global__ void k_hist(const int* __restrict__ rows, int* __restrict__ counts) {
  int e = blockIdx.x * 256 + threadIdx.x;
  if (e < En) atomicAdd(&counts[rows[e]], 1);
}

__global__ __launch_bounds__(1024) void k_scan(const int* __restrict__ counts,
                                               int* __restrict__ ptr) {
  __shared__ int buf[1024];
  __shared__ int s_base;
  const int tid = threadIdx.x;
  if (tid == 0) { s_base = 0; ptr[0] = 0; }
  __syncthreads();
  for (int start = 0; start < Nn; start += 1024) {
    int i = start + tid;
    int v = (i < Nn) ? counts[i] : 0;
    buf[tid] = v;
    __syncthreads();
    for (int off = 1; off < 1024; off <<= 1) {
      int t = (tid >= off) ? buf[tid - off] : 0;
      __syncthreads();
      buf[tid] += t;
      __syncthreads();
    }
    if (i < Nn) ptr[i + 1] = s_base + buf[tid];
    __syncthreads();
    if (tid == 0) s_base += buf[1023];
    __syncthreads();
  }
}

__global__ void k_scatter(const int* __restrict__ rows, const int* __restrict__ cols,
                          const float* __restrict__ w, const int* __restrict__ ptr,
                          int* __restrict__ fill, int* __restrict__ csr_col,
                          float* __restrict__ csr_w) {
  int e = blockIdx.x * 256 + threadIdx.x;
  if (e >= En) return;
  int r = rows[e];
  int pos = atomicAdd(&fill[r], 1);
  int d = ptr[r] + pos;
  csr_col[d] = cols[e];
  csr_w[d] = w[e];
}

// ---------------- SpMM: pb = bf16(0.5 * segment_sum(w * hb[col])) ----------------
__global__ __launch_bounds__(256) void k_spmm(const int* __restrict__ ptr,
    const int* __restrict__ csr_col, const float* __restrict__ csr_w,
    const unsigned short* __restrict__ hb, unsigned short* __restrict__ pb) {
  const int wave = (blockIdx.x * 256 + threadIdx.x) >> 6;
  const int lane = threadIdx.x & 63;
  if (wave >= Nn) return;
  const int s = ptr[wave], e_end = ptr[wave + 1];
  float a0 = 0.f, a1 = 0.f;
  for (int e = s; e < e_end; ++e) {
    const int c = csr_col[e];
    const float w = csr_w[e];
    const unsigned int v = *(const unsigned int*)(hb + (size_t)c * Hd + lane * 2);
    union { unsigned int i; float f; } lo, hi;
    lo.i = v << 16;
    hi.i = v & 0xFFFF0000u;
    a0 += w * lo.f;
    a1 += w * hi.f;
  }
  unsigned int o = (unsigned int)f2bf(0.5f * a0) | ((unsigned int)f2bf(0.5f * a1) << 16);
  *(unsigned int*)(pb + (size_t)wave * Hd + lane * 2) = o;
}

// ---------------- layer (MFMA): gemm = [pb;x0b] @ Wcat[l];
// h = relu(h + (1-b)(p + 0.5 x0) + b*gemm);  write h fp32 + hb bf16
__global__ __launch_bounds__(256) void k_layer(const unsigned short* __restrict__ pb,
    const unsigned short* __restrict__ x0b, const unsigned short* __restrict__ Wcp,
    float* __restrict__ h, unsigned short* __restrict__ hb, float beta) {
  const int tid = threadIdx.x;
  const int wv = tid >> 6, lane = tid & 63;
  const int lrow = lane & 15, quad = lane >> 4;
  const int row0 = blockIdx.x * 64;
  const int ar = row0 + wv * 16 + lrow;   // arrays padded to NR rows -> no guard
  f32x4 acc[8];
#pragma unroll
  for (int t = 0; t < 8; ++t) acc[t] = (f32x4){0.f, 0.f, 0.f, 0.f};

#pragma unroll
  for (int kk = 0; kk < 8; ++kk) {
    const unsigned short* src = (kk < 4) ? pb : x0b;
    const int ko = (kk & 3) * 32 + quad * 8;
    const bf16x8 af = *(const bf16x8*)(src + (size_t)ar * Hd + ko);
#pragma unroll
    for (int nt = 0; nt < 8; ++nt) {
      const bf16x8 bf = *(const bf16x8*)(Wcp + ((size_t)(kk * 4 + quad) * 128 + nt * 16 + lrow) * 8);
      acc[nt] = __builtin_amdgcn_mfma_f32_16x16x32_bf16(af, bf, acc[nt], 0, 0, 0);
    }
  }

  __shared__ float sacc[64 * 132];
#pragma unroll
  for (int nt = 0; nt < 8; ++nt)
#pragma unroll
    for (int i = 0; i < 4; ++i)
      sacc[(wv * 16 + quad * 4 + i) * 132 + nt * 16 + lrow] = acc[nt][i];
  __syncthreads();

  const int row = tid >> 2, cs = (tid & 3) * 32;
  const int gr = row0 + row;
  if (gr < Nn) {
    const float om = 1.f - beta;
#pragma unroll
    for (int g = 0; g < 4; ++g) {
      const int c0 = cs + g * 8;
      const u16x8 pv = *(const u16x8*)(pb + (size_t)gr * Hd + c0);
      const u16x8 xv = *(const u16x8*)(x0b + (size_t)gr * Hd + c0);
      const float4 h0 = *(const float4*)(h + (size_t)gr * Hd + c0);
      const float4 h1 = *(const float4*)(h + (size_t)gr * Hd + c0 + 4);
      float hv[8] = {h0.x, h0.y, h0.z, h0.w, h1.x, h1.y, h1.z, h1.w};
      float nv[8];
#pragma unroll
      for (int j = 0; j < 8; ++j) {
        const float gemm = sacc[row * 132 + c0 + j];
        const float pj = bf2f(pv[j]);
        const float xj = bf2f(xv[j]);
        const float outv = om * (pj + 0.5f * xj) + beta * gemm;
        nv[j] = fmaxf(hv[j] + outv, 0.f);
      }
      float4 o0 = {nv[0], nv[1], nv[2], nv[3]}, o1 = {nv[4], nv[5], nv[6], nv[7]};
      *(float4*)(h + (size_t)gr * Hd + c0) = o0;
      *(float4*)(h + (size_t)gr * Hd + c0 + 4) = o1;
      u16x8 ob;
#pragma unroll
      for (int j = 0; j < 8; ++j) ob[j] = f2bf(nv[j]);
      *(u16x8*)(hb + (size_t)gr * Hd + c0) = ob;
    }
  }
}

// ---------------- head: emb, an_bf16 = emb/||emb||, p_lc = log_softmax(h@W2+b2) ----
__global__ __launch_bounds__(256) void k_head(const float* __restrict__ h,
    const float* __restrict__ W2, const float* __restrict__ b2,
    unsigned short* __restrict__ anb, float* __restrict__ p_lc,
    float* __restrict__ out_emb) {
  const int wid = (blockIdx.x * 256 + threadIdx.x) >> 6;
  const int lane = threadIdx.x & 63;
  if (wid >= Bb) return;
  const float* hr = h + (size_t)wid * Hd;
  const float v0 = hr[lane], v1 = hr[lane + 64];
  out_emb[wid * Hd + lane] = v0;
  out_emb[wid * Hd + lane + 64] = v1;
  float ss = v0 * v0 + v1 * v1;
#pragma unroll
  for (int off = 32; off > 0; off >>= 1) ss += __shfl_xor(ss, off);
  const float inv = 1.f / fmaxf(sqrtf(ss), 1e-8f);
  anb[wid * Hd + lane] = f2bf(v0 * inv);
  anb[wid * Hd + lane + 64] = f2bf(v1 * inv);
  float l = 0.f;
  if (lane < Cc) {
    for (int k = 0; k < Hd; ++k) l += hr[k] * W2[k * Cc + lane];
    l += b2[lane];
  }
  float lm = (lane < Cc) ? l : -3.0e38f;
#pragma unroll
  for (int off = 32; off > 0; off >>= 1) lm = fmaxf(lm, __shfl_xor(lm, off));
  float ex = (lane < Cc) ? expf(l - lm) : 0.f;
#pragma unroll
  for (int off = 32; off > 0; off >>= 1) ex += __shfl_xor(ex, off);
  const float lse = logf(ex);
  if (lane < Cc) p_lc[wid * Cc + lane] = l - lm - lse;
}

// ---------------- fused sim = an@an^T (bf16 MFMA) with running top-5 ----------
#define CH_N  4
#define CH_SZ 2500
#define SB_LD 136
__global__ __launch_bounds__(256) void k_simtopk(const unsigned short* __restrict__ anb,
    float* __restrict__ cval, int* __restrict__ cidx) {
  __shared__ __align__(16) char smem[40960];
  unsigned short* sb = (unsigned short*)smem;
  const int rt = blockIdx.x / CH_N;
  const int chunk = blockIdx.x % CH_N;
  const int row0 = rt * 64;
  const int cbeg = chunk * CH_SZ;
  const int cend = cbeg + CH_SZ;
  const int tid = threadIdx.x;
  const int wv = tid >> 6;
  const int lane = tid & 63;
  const int lrow = lane & 15;
  const int quad = lane >> 4;

  union Frag { uint4 u4; bf16x8 v; };
  bf16x8 afr[4];
  const int ar = row0 + wv * 16 + lrow;
#pragma unroll
  for (int kq = 0; kq < 4; ++kq) {
    Frag f;
    f.u4 = make_uint4(0u, 0u, 0u, 0u);
    if (ar < Bb) f.u4 = *(const uint4*)(anb + (size_t)ar * Hd + kq * 32 + quad * 8);
    afr[kq] = f.v;
  }

  float bv[4][KT];
  int bi[4][KT];
#pragma unroll
  for (int r = 0; r < 4; ++r)
#pragma unroll
    for (int t = 0; t < KT; ++t) { bv[r][t] = -3.0e38f; bi[r][t] = 0x7fffffff; }

  const int ntile = (CH_SZ + 63) / 64;
  for (int t = 0; t < ntile; ++t) {
    const int c0 = cbeg + t * 64;
    __syncthreads();
    for (int i = tid; i < 1024; i += 256) {
      const int r = i >> 4, ch = i & 15;
      const int gc = c0 + r;
      uint4 v = make_uint4(0u, 0u, 0u, 0u);
      if (gc < cend) v = *(const uint4*)(anb + (size_t)gc * Hd + ch * 8);
      *(uint4*)&sb[r * SB_LD + ch * 8] = v;
    }
    __syncthreads();
#pragma unroll
    for (int sub = 0; sub < 4; ++sub) {
      f32x4 acc = {0.f, 0.f, 0.f, 0.f};
      const int scol = sub * 16 + lrow;
#pragma unroll
      for (int kq = 0; kq < 4; ++kq) {
        bf16x8 bfr = *(const bf16x8*)&sb[scol * SB_LD + kq * 32 + quad * 8];
        acc = __builtin_amdgcn_mfma_f32_16x16x32_bf16(afr[kq], bfr, acc, 0, 0, 0);
      }
      const int gc = c0 + scol;
      const bool ok = gc < cend;
#pragma unroll
      for (int i = 0; i < 4; ++i) {
        const float v = ok ? acc[i] : -3.0e38f;
        if (v > bv[i][KT - 1]) {
          float tv = v; int ti = gc;
#pragma unroll
          for (int s = 0; s < KT; ++s) {
            if (tv > bv[i][s]) {
              float ov = bv[i][s]; int oi = bi[i][s];
              bv[i][s] = tv; bi[i][s] = ti; tv = ov; ti = oi;
            }
          }
        }
      }
    }
  }

  __syncthreads();
  float* mv = (float*)smem;
  int* mi = (int*)(smem + 20480);
#pragma unroll
  for (int i = 0; i < 4; ++i) {
    const int row = wv * 16 + quad * 4 + i;
#pragma unroll
    for (int t = 0; t < KT; ++t) {
      mv[row * 80 + lrow * KT + t] = bv[i][t];
      mi[row * 80 + lrow * KT + t] = bi[i][t];
    }
  }
  __syncthreads();
  if (tid < 64) {
    const int gr = row0 + tid;
    if (gr < Bb) {
      float tv5[KT]; int ti5[KT];
#pragma unroll
      for (int t = 0; t < KT; ++t) { tv5[t] = -3.0e38f; ti5[t] = 0x7fffffff; }
      for (int m = 0; m < 80; ++m) {
        float v = mv[tid * 80 + m]; int id = mi[tid * 80 + m];
        if (v > tv5[KT - 1] || (v == tv5[KT - 1] && id < ti5[KT - 1])) {
#pragma unroll
          for (int s = 0; s < KT; ++s) {
            if (v > tv5[s] || (v == tv5[s] && id < ti5[s])) {
              float ov = tv5[s]; int oi = ti5[s];
              tv5[s] = v; ti5[s] = id; v = ov; id = oi;
            }
          }
        }
      }
#pragma unroll
      for (int t = 0; t < KT; ++t) {
        cval[gr * (CH_N * KT) + chunk * KT + t] = tv5[t];
        cidx[gr * (CH_N * KT) + chunk * KT + t] = ti5[t];
      }
    }
  }
}

// ---------------- final ----------------
__global__ __launch_bounds__(256) void k_final(const float* __restrict__ cval,
    const int* __restrict__ cidx, const int* __restrict__ y,
    const float* __restrict__ p_lc, float* __restrict__ out_final) {
  const int b = blockIdx.x * 256 + threadIdx.x;
  if (b >= Bb) return;
  float tv5[KT]; int ti5[KT];
#pragma unroll
  for (int t = 0; t < KT; ++t) { tv5[t] = -3.0e38f; ti5[t] = 0x7fffffff; }
#pragma unroll
  for (int m = 0; m < CH_N * KT; ++m) {
    float v = cval[b * (CH_N * KT) + m]; int id = cidx[b * (CH_N * KT) + m];
    if (v > tv5[KT - 1] || (v == tv5[KT - 1] && id < ti5[KT - 1])) {
#pragma unroll
      for (int t = 0; t < KT; ++t) {
        if (v > tv5[t] || (v == tv5[t] && id < ti5[t])) {
          float ov = tv5[t]; int oi = ti5[t];
          tv5[t] = v; ti5[t] = id; v = ov; id = oi;
        }
      }
    }
  }
  float w[KT]; int cls[KT];
#pragma unroll
  for (int t = 0; t < KT; ++t) { w[t] = expf(tv5[t]); cls[t] = y[ti5[t]]; }
  float m = -3.0e38f;
  for (int c = 0; c < Cc; ++c) {
    float f = 0.f;
#pragma unroll
    for (int t = 0; t < KT; ++t) f += (cls[t] == c) ? w[t] : 0.f;
    m = fmaxf(m, f);
  }
  float s = 0.f;
  for (int c = 0; c < Cc; ++c) {
    float f = 0.f;
#pragma unroll
    for (int t = 0; t < KT; ++t) f += (cls[t] == c) ? w[t] : 0.f;
    s += expf(f - m);
  }
  const float lse = logf(s);
  for (int c = 0; c < Cc; ++c) {
    float f = 0.f;
#pragma unroll
    for (int t = 0; t < KT; ++t) f += (cls[t] == c) ? w[t] : 0.f;
    out_final[b * Cc + c] = 0.5f * p_lc[b * Cc + c] + 0.5f * (f - m - lse);
  }
}

extern "C" void kernel_launch(void* const* d_in, const int* in_sizes, int n_in,
                              void* d_out, int out_size, void* d_ws, size_t ws_size,
                              hipStream_t stream) {
  const float* x  = (const float*)d_in[0];
  const int* erow = (const int*)d_in[1];
  const int* ecol = erow + En;
  const float* ew = (const float*)d_in[2];
  const int* y    = (const int*)d_in[3];
  const float* W1 = (const float*)d_in[5];
  const float* b1 = (const float*)d_in[6];
  const float* cw1 = (const float*)d_in[7];
  const float* cw2 = (const float*)d_in[8];
  const float* W2 = (const float*)d_in[9];
  const float* b2 = (const float*)d_in[10];
  float* out = (float*)d_out;

  float* ws = (float*)d_ws;
  size_t off = 0;
  float* h   = ws + off; off += (size_t)NR * Hd;
  float* plc = ws + off; off += (size_t)Bb * Cc;
  float* cval = ws + off; off += (size_t)Bb * (CH_N * KT);
  int* cidx  = (int*)(ws + off); off += (size_t)Bb * (CH_N * KT);
  int* counts = (int*)(ws + off); off += Nn;
  int* fill   = (int*)(ws + off); off += Nn;
  int* rptr   = (int*)(ws + off); off += Nn + 4;
  int* ccol   = (int*)(ws + off); off += En;
  float* cwt  = ws + off; off += En;
  unsigned short* anb = (unsigned short*)(ws + off); off += (size_t)Bb * Hd / 2;
  unsigned short* hb  = (unsigned short*)(ws + off); off += (size_t)NR * Hd / 2;
  unsigned short* x0b = (unsigned short*)(ws + off); off += (size_t)NR * Hd / 2;
  unsigned short* pb  = (unsigned short*)(ws + off); off += (size_t)NR * Hd / 2;
  unsigned short* W1p = (unsigned short*)(ws + off); off += 65536 / 2;
  unsigned short* Wcp = (unsigned short*)(ws + off); off += 294912 / 2;

  k_pack_w1<<<256, 256, 0, stream>>>(W1, W1p);
  k_pack_wc<<<1152, 256, 0, stream>>>(cw1, cw2, Wcp);
  k_in<<<NR / 64, 256, 0, stream>>>(x, W1p, b1, h, hb, x0b);
  hipMemsetAsync(counts, 0, (size_t)2 * Nn * sizeof(int), stream);
  k_hist<<<(En + 255) / 256, 256, 0, stream>>>(erow, counts);
  k_scan<<<1, 1024, 0, stream>>>(counts, rptr);
  k_scatter<<<(En + 255) / 256, 256, 0, stream>>>(erow, ecol, ew, rptr, fill, ccol, cwt);
  for (int l = 0; l < Ll; ++l) {
    const float beta = logf(1.0f / (float)(l + 1) + 1.0f);
    k_spmm<<<(Nn * 64 + 255) / 256, 256, 0, stream>>>(rptr, ccol, cwt, hb, pb);
    k_layer<<<NR / 64, 256, 0, stream>>>(pb, x0b, Wcp + (size_t)l * 32768, h, hb, beta);
  }
  k_head<<<(Bb * 64) / 256, 256, 0, stream>>>(h, W2, b2, anb, plc, out + (size_t)Bb * Cc);
  k_simtopk<<<((Bb + 63) / 64) * CH_N, 256, 0, stream>>>(anb, cval, cidx);
  k_final<<<(Bb + 255) / 256, 256, 0, stream>>>(cval, cidx, y, plc, out);
}

// Round 4
// 1292.535 us; speedup vs baseline: 2.5105x; 1.2354x over previous
//
#include <hip/hip_runtime.h>
#include <hip/hip_bf16.h>
#include <math.h>

#define Nn  50000
#define NR  50048   // rows padded to 64
#define En  800000
#define DIN 500
#define Hd  128
#define Cc  40
#define Bb  10000
#define Ll  9
#define KT  5

typedef short bf16x8 __attribute__((ext_vector_type(8)));
typedef unsigned short u16x8 __attribute__((ext_vector_type(8)));
typedef float f32x4 __attribute__((ext_vector_type(4)));

__device__ inline float bf2f(unsigned short u) {
  union { unsigned int i; float f; } c; c.i = (unsigned int)u << 16; return c.f;
}
__device__ inline unsigned short f2bf(float f) {
  __hip_bfloat16 b = __float2bfloat16(f);
  return *(unsigned short*)&b;
}

// ---------------- weight packing into B-fragment layout ----------------
__global__ __launch_bounds__(256) void k_pack_w1(const float* __restrict__ W1,
                                                 unsigned short* __restrict__ W1p) {
  const int id = blockIdx.x * 256 + threadIdx.x;   // 16*4*128*8 = 65536
  if (id >= 65536) return;
  const int j = id & 7, col = (id >> 3) & 127, qk = id >> 10;  // qk = kk*4+quad
  const int k = (qk >> 2) * 32 + (qk & 3) * 8 + j;
  W1p[id] = f2bf((k < DIN) ? W1[(size_t)k * Hd + col] : 0.f);
}

// Wcat[l] = [W1l ; 0.5*W2l]  (K=256), same frag packing, 32768 elems/layer
__global__ __launch_bounds__(256) void k_pack_wc(const float* __restrict__ cw1,
    const float* __restrict__ cw2, unsigned short* __restrict__ Wcp) {
  const int id = blockIdx.x * 256 + threadIdx.x;   // 9*32768 = 294912
  if (id >= 294912) return;
  const int j = id & 7, col = (id >> 3) & 127, qk = (id >> 10) & 31, l = id >> 15;
  const int k = (qk >> 2) * 32 + (qk & 3) * 8 + j;  // 0..255
  float v;
  if (k < 128) v = cw1[((size_t)l * 128 + k) * 128 + col];
  else         v = 0.5f * cw2[((size_t)l * 128 + (k - 128)) * 128 + col];
  Wcp[id] = f2bf(v);
}

// ---------------- input GEMM (MFMA): h = relu(x @ W1 + b1) ----------------
__global__ __launch_bounds__(256) void k_in(const float* __restrict__ x,
    const unsigned short* __restrict__ W1p, const float* __restrict__ b1,
    float* __restrict__ h, unsigned short* __restrict__ hb,
    unsigned short* __restrict__ x0b) {
  const int tid = threadIdx.x;
  const int wv = tid >> 6, lane = tid & 63;
  const int lrow = lane & 15, quad = lane >> 4;
  const int row0 = blockIdx.x * 64;
  const int ar = row0 + wv * 16 + lrow;
  f32x4 acc[8];
#pragma unroll
  for (int t = 0; t < 8; ++t) acc[t] = (f32x4){0.f, 0.f, 0.f, 0.f};

  for (int kk = 0; kk < 16; ++kk) {
    const int kbase = kk * 32 + quad * 8;
    float av[8];
    if (ar < Nn) {
      if (kk < 15) {
        const float4 p0 = *(const float4*)(x + (size_t)ar * DIN + kbase);
        const float4 p1 = *(const float4*)(x + (size_t)ar * DIN + kbase + 4);
        av[0] = p0.x; av[1] = p0.y; av[2] = p0.z; av[3] = p0.w;
        av[4] = p1.x; av[5] = p1.y; av[6] = p1.z; av[7] = p1.w;
      } else {
#pragma unroll
        for (int j = 0; j < 8; ++j)
          av[j] = (kbase + j < DIN) ? x[(size_t)ar * DIN + kbase + j] : 0.f;
      }
    } else {
#pragma unroll
      for (int j = 0; j < 8; ++j) av[j] = 0.f;
    }
    bf16x8 af;
#pragma unroll
    for (int j = 0; j < 8; ++j) af[j] = (short)f2bf(av[j]);
#pragma unroll
    for (int nt = 0; nt < 8; ++nt) {
      const bf16x8 bf = *(const bf16x8*)(W1p + ((size_t)(kk * 4 + quad) * 128 + nt * 16 + lrow) * 8);
      acc[nt] = __builtin_amdgcn_mfma_f32_16x16x32_bf16(af, bf, acc[nt], 0, 0, 0);
    }
  }

  __shared__ float sacc[64 * 132];
#pragma unroll
  for (int nt = 0; nt < 8; ++nt)
#pragma unroll
    for (int i = 0; i < 4; ++i)
      sacc[(wv * 16 + quad * 4 + i) * 132 + nt * 16 + lrow] = acc[nt][i];
  __syncthreads();

  const int row = tid >> 2, cs = (tid & 3) * 32;
  const int gr = row0 + row;
  if (gr < Nn) {
#pragma unroll
    for (int g = 0; g < 4; ++g) {
      const int c0 = cs + g * 8;
      float v[8];
#pragma unroll
      for (int j = 0; j < 8; ++j)
        v[j] = fmaxf(sacc[row * 132 + c0 + j] + b1[c0 + j], 0.f);
      float4 o0 = {v[0], v[1], v[2], v[3]}, o1 = {v[4], v[5], v[6], v[7]};
      *(float4*)(h + (size_t)gr * Hd + c0) = o0;
      *(float4*)(h + (size_t)gr * Hd + c0 + 4) = o1;
      u16x8 ob;
#pragma unroll
      for (int j = 0; j < 8; ++j) ob[j] = f2bf(v[j]);
      *(u16x8*)(hb + (size_t)gr * Hd + c0) = ob;
      *(u16x8*)(x0b + (size_t)gr * Hd + c0) = ob;
    }
  }
}

// ---------------- CSR build ----------------
__global__ void k_hist(const int* __restrict__ rows, int* __restrict__ counts) {
  int e = blockIdx.x * 256 + threadIdx.x;
  if (e < En) atomicAdd(&counts[rows[e]], 1);
}

__global__ __launch_bounds__(1024) void k_scan(const int* __restrict__ counts,
                                               int* __restrict__ ptr) {
  __shared__ int buf[1024];
  __shared__ int s_base;
  const int tid = threadIdx.x;
  if (tid == 0) { s_base = 0; ptr[0] = 0; }
  __syncthreads();
  for (int start = 0; start < Nn; start += 1024) {
    int i = start + tid;
    int v = (i < Nn) ? counts[i] : 0;
    buf[tid] = v;
    __syncthreads();
    for (int off = 1; off < 1024; off <<= 1) {
      int t = (tid >= off) ? buf[tid - off] : 0;
      __syncthreads();
      buf[tid] += t;
      __syncthreads();
    }
    if (i < Nn) ptr[i + 1] = s_base + buf[tid];
    __syncthreads();
    if (tid == 0) s_base += buf[1023];
    __syncthreads();
  }
}

__global__ void k_scatter(const int* __restrict__ rows, const int* __restrict__ cols,
                          const float* __restrict__ w, const int* __restrict__ ptr,
                          int* __restrict__ fill, int* __restrict__ csr_col,
                          float* __restrict__ csr_w) {
  int e = blockIdx.x * 256 + threadIdx.x;
  if (e >= En) return;
  int r = rows[e];
  int pos = atomicAdd(&fill[r], 1);
  int d = ptr[r] + pos;
  csr_col[d] = cols[e];
  csr_w[d] = w[e];
}

// ---------------- SpMM: pb = bf16(0.5 * segment_sum(w * hb[col])) ----------------
__global__ __launch_bounds__(256) void k_spmm(const int* __restrict__ ptr,
    const int* __restrict__ csr_col, const float* __restrict__ csr_w,
    const unsigned short* __restrict__ hb, unsigned short* __restrict__ pb) {
  const int wave = (blockIdx.x * 256 + threadIdx.x) >> 6;
  const int lane = threadIdx.x & 63;
  if (wave >= Nn) return;
  const int s = ptr[wave], e_end = ptr[wave + 1];
  float a0 = 0.f, a1 = 0.f;
  int e = s;
  for (; e + 4 <= e_end; e += 4) {
    const int c0 = csr_col[e], c1 = csr_col[e + 1], c2 = csr_col[e + 2], c3 = csr_col[e + 3];
    const float w0 = csr_w[e], w1 = csr_w[e + 1], w2 = csr_w[e + 2], w3 = csr_w[e + 3];
    const unsigned int v0 = *(const unsigned int*)(hb + (size_t)c0 * Hd + lane * 2);
    const unsigned int v1 = *(const unsigned int*)(hb + (size_t)c1 * Hd + lane * 2);
    const unsigned int v2 = *(const unsigned int*)(hb + (size_t)c2 * Hd + lane * 2);
    const unsigned int v3 = *(const unsigned int*)(hb + (size_t)c3 * Hd + lane * 2);
    union { unsigned int i; float f; } t;
    t.i = v0 << 16;        a0 += w0 * t.f;
    t.i = v0 & 0xFFFF0000u; a1 += w0 * t.f;
    t.i = v1 << 16;        a0 += w1 * t.f;
    t.i = v1 & 0xFFFF0000u; a1 += w1 * t.f;
    t.i = v2 << 16;        a0 += w2 * t.f;
    t.i = v2 & 0xFFFF0000u; a1 += w2 * t.f;
    t.i = v3 << 16;        a0 += w3 * t.f;
    t.i = v3 & 0xFFFF0000u; a1 += w3 * t.f;
  }
  for (; e < e_end; ++e) {
    const int c = csr_col[e];
    const float w = csr_w[e];
    const unsigned int v = *(const unsigned int*)(hb + (size_t)c * Hd + lane * 2);
    union { unsigned int i; float f; } lo, hi;
    lo.i = v << 16;
    hi.i = v & 0xFFFF0000u;
    a0 += w * lo.f;
    a1 += w * hi.f;
  }
  unsigned int o = (unsigned int)f2bf(0.5f * a0) | ((unsigned int)f2bf(0.5f * a1) << 16);
  *(unsigned int*)(pb + (size_t)wave * Hd + lane * 2) = o;
}

// ---------------- layer (MFMA) ----------------
__global__ __launch_bounds__(256) void k_layer(const unsigned short* __restrict__ pb,
    const unsigned short* __restrict__ x0b, const unsigned short* __restrict__ Wcp,
    float* __restrict__ h, unsigned short* __restrict__ hb, float beta) {
  const int tid = threadIdx.x;
  const int wv = tid >> 6, lane = tid & 63;
  const int lrow = lane & 15, quad = lane >> 4;
  const int row0 = blockIdx.x * 64;
  const int ar = row0 + wv * 16 + lrow;
  f32x4 acc[8];
#pragma unroll
  for (int t = 0; t < 8; ++t) acc[t] = (f32x4){0.f, 0.f, 0.f, 0.f};

#pragma unroll
  for (int kk = 0; kk < 8; ++kk) {
    const unsigned short* src = (kk < 4) ? pb : x0b;
    const int ko = (kk & 3) * 32 + quad * 8;
    const bf16x8 af = *(const bf16x8*)(src + (size_t)ar * Hd + ko);
#pragma unroll
    for (int nt = 0; nt < 8; ++nt) {
      const bf16x8 bf = *(const bf16x8*)(Wcp + ((size_t)(kk * 4 + quad) * 128 + nt * 16 + lrow) * 8);
      acc[nt] = __builtin_amdgcn_mfma_f32_16x16x32_bf16(af, bf, acc[nt], 0, 0, 0);
    }
  }

  __shared__ float sacc[64 * 132];
#pragma unroll
  for (int nt = 0; nt < 8; ++nt)
#pragma unroll
    for (int i = 0; i < 4; ++i)
      sacc[(wv * 16 + quad * 4 + i) * 132 + nt * 16 + lrow] = acc[nt][i];
  __syncthreads();

  const int row = tid >> 2, cs = (tid & 3) * 32;
  const int gr = row0 + row;
  if (gr < Nn) {
    const float om = 1.f - beta;
#pragma unroll
    for (int g = 0; g < 4; ++g) {
      const int c0 = cs + g * 8;
      const u16x8 pv = *(const u16x8*)(pb + (size_t)gr * Hd + c0);
      const u16x8 xv = *(const u16x8*)(x0b + (size_t)gr * Hd + c0);
      const float4 h0 = *(const float4*)(h + (size_t)gr * Hd + c0);
      const float4 h1 = *(const float4*)(h + (size_t)gr * Hd + c0 + 4);
      float hv[8] = {h0.x, h0.y, h0.z, h0.w, h1.x, h1.y, h1.z, h1.w};
      float nv[8];
#pragma unroll
      for (int j = 0; j < 8; ++j) {
        const float gemm = sacc[row * 132 + c0 + j];
        const float pj = bf2f(pv[j]);
        const float xj = bf2f(xv[j]);
        const float outv = om * (pj + 0.5f * xj) + beta * gemm;
        nv[j] = fmaxf(hv[j] + outv, 0.f);
      }
      float4 o0 = {nv[0], nv[1], nv[2], nv[3]}, o1 = {nv[4], nv[5], nv[6], nv[7]};
      *(float4*)(h + (size_t)gr * Hd + c0) = o0;
      *(float4*)(h + (size_t)gr * Hd + c0 + 4) = o1;
      u16x8 ob;
#pragma unroll
      for (int j = 0; j < 8; ++j) ob[j] = f2bf(nv[j]);
      *(u16x8*)(hb + (size_t)gr * Hd + c0) = ob;
    }
  }
}

// ---------------- head ----------------
__global__ __launch_bounds__(256) void k_head(const float* __restrict__ h,
    const float* __restrict__ W2, const float* __restrict__ b2,
    unsigned short* __restrict__ anb, float* __restrict__ p_lc,
    float* __restrict__ out_emb) {
  const int wid = (blockIdx.x * 256 + threadIdx.x) >> 6;
  const int lane = threadIdx.x & 63;
  if (wid >= Bb) return;
  const float* hr = h + (size_t)wid * Hd;
  const float v0 = hr[lane], v1 = hr[lane + 64];
  out_emb[wid * Hd + lane] = v0;
  out_emb[wid * Hd + lane + 64] = v1;
  float ss = v0 * v0 + v1 * v1;
#pragma unroll
  for (int off = 32; off > 0; off >>= 1) ss += __shfl_xor(ss, off);
  const float inv = 1.f / fmaxf(sqrtf(ss), 1e-8f);
  anb[wid * Hd + lane] = f2bf(v0 * inv);
  anb[wid * Hd + lane + 64] = f2bf(v1 * inv);
  float l = 0.f;
  if (lane < Cc) {
    for (int k = 0; k < Hd; ++k) l += hr[k] * W2[k * Cc + lane];
    l += b2[lane];
  }
  float lm = (lane < Cc) ? l : -3.0e38f;
#pragma unroll
  for (int off = 32; off > 0; off >>= 1) lm = fmaxf(lm, __shfl_xor(lm, off));
  float ex = (lane < Cc) ? expf(l - lm) : 0.f;
#pragma unroll
  for (int off = 32; off > 0; off >>= 1) ex += __shfl_xor(ex, off);
  const float lse = logf(ex);
  if (lane < Cc) p_lc[wid * Cc + lane] = l - lm - lse;
}

// ---------------- fused sim = an@an^T (bf16 MFMA) + gated running top-5 -------
// block 512 = 8 waves x 16 rows = 128 rows; CH_N=8 col chunks of 1250.
#define CH_N  8
#define CH_SZ 1250
#define SB_LD 136
__global__ __launch_bounds__(512) void k_simtopk(const unsigned short* __restrict__ anb,
    float* __restrict__ cval, int* __restrict__ cidx) {
  __shared__ __align__(16) char smem[40960];   // staging 17408 B | merge 40960 B
  unsigned short* sb = (unsigned short*)smem;
  const int rt = blockIdx.x / CH_N;
  const int chunk = blockIdx.x % CH_N;
  const int row0 = rt * 128;
  const int cbeg = chunk * CH_SZ;
  const int cend = cbeg + CH_SZ;
  const int tid = threadIdx.x;
  const int wv = tid >> 6;
  const int lane = tid & 63;
  const int lrow = lane & 15;
  const int quad = lane >> 4;

  union Frag { uint4 u4; bf16x8 v; };
  bf16x8 afr[4];
  const int ar = row0 + wv * 16 + lrow;
#pragma unroll
  for (int kq = 0; kq < 4; ++kq) {
    Frag f;
    f.u4 = make_uint4(0u, 0u, 0u, 0u);
    if (ar < Bb) f.u4 = *(const uint4*)(anb + (size_t)ar * Hd + kq * 32 + quad * 8);
    afr[kq] = f.v;
  }

  float bv[4][KT];
  int bi[4][KT];
#pragma unroll
  for (int r = 0; r < 4; ++r)
#pragma unroll
    for (int t = 0; t < KT; ++t) { bv[r][t] = -3.0e38f; bi[r][t] = 0x7fffffff; }

  const int ntile = (CH_SZ + 63) / 64;   // 20
  for (int t = 0; t < ntile; ++t) {
    const int c0 = cbeg + t * 64;
    __syncthreads();
#pragma unroll
    for (int it = 0; it < 2; ++it) {         // 64 cols x 16 uint4 = 1024 chunks
      const int i = tid + it * 512;
      const int r = i >> 4, ch = i & 15;
      const int gc = c0 + r;
      uint4 v = make_uint4(0u, 0u, 0u, 0u);
      if (gc < cend) v = *(const uint4*)(anb + (size_t)gc * Hd + ch * 8);
      *(uint4*)&sb[r * SB_LD + ch * 8] = v;
    }
    __syncthreads();
    f32x4 accs[4];
#pragma unroll
    for (int sub = 0; sub < 4; ++sub) {
      f32x4 acc = {0.f, 0.f, 0.f, 0.f};
      const int scol = sub * 16 + lrow;
#pragma unroll
      for (int kq = 0; kq < 4; ++kq) {
        bf16x8 bfr = *(const bf16x8*)&sb[scol * SB_LD + kq * 32 + quad * 8];
        acc = __builtin_amdgcn_mfma_f32_16x16x32_bf16(afr[kq], bfr, acc, 0, 0, 0);
      }
      accs[sub] = acc;
    }
    // gated top-5: one compare per row in the fast path
#pragma unroll
    for (int i = 0; i < 4; ++i) {
      const float m = fmaxf(fmaxf(accs[0][i], accs[1][i]), fmaxf(accs[2][i], accs[3][i]));
      if (m > bv[i][KT - 1]) {
#pragma unroll
        for (int sub = 0; sub < 4; ++sub) {     // ascending col => lowest-idx tie pref
          const int gc = c0 + sub * 16 + lrow;
          const float v = accs[sub][i];
          if (gc < cend && v > bv[i][KT - 1]) {
            float tv = v; int ti = gc;
#pragma unroll
            for (int s = 0; s < KT; ++s) {
              if (tv > bv[i][s]) {
                float ov = bv[i][s]; int oi = bi[i][s];
                bv[i][s] = tv; bi[i][s] = ti; tv = ov; ti = oi;
              }
            }
          }
        }
      }
    }
  }

  // merge: two 64-row phases through 40 KB LDS
  float* mv = (float*)smem;                  // [64][80]
  int* mi = (int*)(smem + 20480);
#pragma unroll
  for (int phase = 0; phase < 2; ++phase) {
    __syncthreads();
    if ((wv >> 2) == phase) {
#pragma unroll
      for (int i = 0; i < 4; ++i) {
        const int lr = (wv & 3) * 16 + quad * 4 + i;
#pragma unroll
        for (int t = 0; t < KT; ++t) {
          mv[lr * 80 + lrow * KT + t] = bv[i][t];
          mi[lr * 80 + lrow * KT + t] = bi[i][t];
        }
      }
    }
    __syncthreads();
    if (tid < 64) {
      const int gr = row0 + phase * 64 + tid;
      if (gr < Bb) {
        float tv5[KT]; int ti5[KT];
#pragma unroll
        for (int t = 0; t < KT; ++t) { tv5[t] = -3.0e38f; ti5[t] = 0x7fffffff; }
        for (int m = 0; m < 80; ++m) {
          float v = mv[tid * 80 + m]; int id = mi[tid * 80 + m];
          if (v > tv5[KT - 1] || (v == tv5[KT - 1] && id < ti5[KT - 1])) {
#pragma unroll
            for (int s = 0; s < KT; ++s) {
              if (v > tv5[s] || (v == tv5[s] && id < ti5[s])) {
                float ov = tv5[s]; int oi = ti5[s];
                tv5[s] = v; ti5[s] = id; v = ov; id = oi;
              }
            }
          }
        }
#pragma unroll
        for (int t = 0; t < KT; ++t) {
          cval[gr * (CH_N * KT) + chunk * KT + t] = tv5[t];
          cidx[gr * (CH_N * KT) + chunk * KT + t] = ti5[t];
        }
      }
    }
  }
}

// ---------------- final ----------------
__global__ __launch_bounds__(256) void k_final(const float* __restrict__ cval,
    const int* __restrict__ cidx, const int* __restrict__ y,
    const float* __restrict__ p_lc, float* __restrict__ out_final) {
  const int b = blockIdx.x * 256 + threadIdx.x;
  if (b >= Bb) return;
  float tv5[KT]; int ti5[KT];
#pragma unroll
  for (int t = 0; t < KT; ++t) { tv5[t] = -3.0e38f; ti5[t] = 0x7fffffff; }
#pragma unroll
  for (int m = 0; m < CH_N * KT; ++m) {
    float v = cval[b * (CH_N * KT) + m]; int id = cidx[b * (CH_N * KT) + m];
    if (v > tv5[KT - 1] || (v == tv5[KT - 1] && id < ti5[KT - 1])) {
#pragma unroll
      for (int t = 0; t < KT; ++t) {
        if (v > tv5[t] || (v == tv5[t] && id < ti5[t])) {
          float ov = tv5[t]; int oi = ti5[t];
          tv5[t] = v; ti5[t] = id; v = ov; id = oi;
        }
      }
    }
  }
  float w[KT]; int cls[KT];
#pragma unroll
  for (int t = 0; t < KT; ++t) { w[t] = expf(tv5[t]); cls[t] = y[ti5[t]]; }
  float m = -3.0e38f;
  for (int c = 0; c < Cc; ++c) {
    float f = 0.f;
#pragma unroll
    for (int t = 0; t < KT; ++t) f += (cls[t] == c) ? w[t] : 0.f;
    m = fmaxf(m, f);
  }
  float s = 0.f;
  for (int c = 0; c < Cc; ++c) {
    float f = 0.f;
#pragma unroll
    for (int t = 0; t < KT; ++t) f += (cls[t] == c) ? w[t] : 0.f;
    s += expf(f - m);
  }
  const float lse = logf(s);
  for (int c = 0; c < Cc; ++c) {
    float f = 0.f;
#pragma unroll
    for (int t = 0; t < KT; ++t) f += (cls[t] == c) ? w[t] : 0.f;
    out_final[b * Cc + c] = 0.5f * p_lc[b * Cc + c] + 0.5f * (f - m - lse);
  }
}

extern "C" void kernel_launch(void* const* d_in, const int* in_sizes, int n_in,
                              void* d_out, int out_size, void* d_ws, size_t ws_size,
                              hipStream_t stream) {
  const float* x  = (const float*)d_in[0];
  const int* erow = (const int*)d_in[1];
  const int* ecol = erow + En;
  const float* ew = (const float*)d_in[2];
  const int* y    = (const int*)d_in[3];
  const float* W1 = (const float*)d_in[5];
  const float* b1 = (const float*)d_in[6];
  const float* cw1 = (const float*)d_in[7];
  const float* cw2 = (const float*)d_in[8];
  const float* W2 = (const float*)d_in[9];
  const float* b2 = (const float*)d_in[10];
  float* out = (float*)d_out;

  float* ws = (float*)d_ws;
  size_t off = 0;
  float* h   = ws + off; off += (size_t)NR * Hd;
  float* plc = ws + off; off += (size_t)Bb * Cc;
  float* cval = ws + off; off += (size_t)Bb * (CH_N * KT);
  int* cidx  = (int*)(ws + off); off += (size_t)Bb * (CH_N * KT);
  int* counts = (int*)(ws + off); off += Nn;
  int* fill   = (int*)(ws + off); off += Nn;
  int* rptr   = (int*)(ws + off); off += Nn + 4;
  int* ccol   = (int*)(ws + off); off += En;
  float* cwt  = ws + off; off += En;
  unsigned short* anb = (unsigned short*)(ws + off); off += (size_t)Bb * Hd / 2;
  unsigned short* hb  = (unsigned short*)(ws + off); off += (size_t)NR * Hd / 2;
  unsigned short* x0b = (unsigned short*)(ws + off); off += (size_t)NR * Hd / 2;
  unsigned short* pb  = (unsigned short*)(ws + off); off += (size_t)NR * Hd / 2;
  unsigned short* W1p = (unsigned short*)(ws + off); off += 65536 / 2;
  unsigned short* Wcp = (unsigned short*)(ws + off); off += 294912 / 2;

  k_pack_w1<<<256, 256, 0, stream>>>(W1, W1p);
  k_pack_wc<<<1152, 256, 0, stream>>>(cw1, cw2, Wcp);
  k_in<<<NR / 64, 256, 0, stream>>>(x, W1p, b1, h, hb, x0b);
  hipMemsetAsync(counts, 0, (size_t)2 * Nn * sizeof(int), stream);
  k_hist<<<(En + 255) / 256, 256, 0, stream>>>(erow, counts);
  k_scan<<<1, 1024, 0, stream>>>(counts, rptr);
  k_scatter<<<(En + 255) / 256, 256, 0, stream>>>(erow, ecol, ew, rptr, fill, ccol, cwt);
  for (int l = 0; l < Ll; ++l) {
    const float beta = logf(1.0f / (float)(l + 1) + 1.0f);
    k_spmm<<<(Nn * 64 + 255) / 256, 256, 0, stream>>>(rptr, ccol, cwt, hb, pb);
    k_layer<<<NR / 64, 256, 0, stream>>>(pb, x0b, Wcp + (size_t)l * 32768, h, hb, beta);
  }
  k_head<<<(Bb * 64) / 256, 256, 0, stream>>>(h, W2, b2, anb, plc, out + (size_t)Bb * Cc);
  k_simtopk<<<((Bb + 127) / 128) * CH_N, 512, 0, stream>>>(anb, cval, cidx);
  k_final<<<(Bb + 255) / 256, 256, 0, stream>>>(cval, cidx, y, plc, out);
}

// Round 5
// 1198.060 us; speedup vs baseline: 2.7085x; 1.0789x over previous
//
#include <hip/hip_runtime.h>
#include <hip/hip_bf16.h>
#include <math.h>

#define Nn  50000
#define NR  50048   // rows padded to 64
#define En  800000
#define DIN 500
#define Hd  128
#define Cc  40
#define Bb  10000
#define Ll  9
#define KT  5

typedef short bf16x8 __attribute__((ext_vector_type(8)));
typedef unsigned short u16x8 __attribute__((ext_vector_type(8)));
typedef float f32x4 __attribute__((ext_vector_type(4)));

__device__ inline float bf2f(unsigned short u) {
  union { unsigned int i; float f; } c; c.i = (unsigned int)u << 16; return c.f;
}
__device__ inline unsigned short f2bf(float f) {
  __hip_bfloat16 b = __float2bfloat16(f);
  return *(unsigned short*)&b;
}

// ---------------- weight packing into B-fragment layout ----------------
__global__ __launch_bounds__(256) void k_pack_w1(const float* __restrict__ W1,
                                                 unsigned short* __restrict__ W1p) {
  const int id = blockIdx.x * 256 + threadIdx.x;   // 16*4*128*8 = 65536
  if (id >= 65536) return;
  const int j = id & 7, col = (id >> 3) & 127, qk = id >> 10;  // qk = kk*4+quad
  const int k = (qk >> 2) * 32 + (qk & 3) * 8 + j;
  W1p[id] = f2bf((k < DIN) ? W1[(size_t)k * Hd + col] : 0.f);
}

// Wcat[l] = [W1l ; 0.5*W2l]  (K=256), same frag packing, 32768 elems/layer
__global__ __launch_bounds__(256) void k_pack_wc(const float* __restrict__ cw1,
    const float* __restrict__ cw2, unsigned short* __restrict__ Wcp) {
  const int id = blockIdx.x * 256 + threadIdx.x;   // 9*32768 = 294912
  if (id >= 294912) return;
  const int j = id & 7, col = (id >> 3) & 127, qk = (id >> 10) & 31, l = id >> 15;
  const int k = (qk >> 2) * 32 + (qk & 3) * 8 + j;  // 0..255
  float v;
  if (k < 128) v = cw1[((size_t)l * 128 + k) * 128 + col];
  else         v = 0.5f * cw2[((size_t)l * 128 + (k - 128)) * 128 + col];
  Wcp[id] = f2bf(v);
}

// ---------------- input GEMM (MFMA): h = relu(x @ W1 + b1) ----------------
__global__ __launch_bounds__(256) void k_in(const float* __restrict__ x,
    const unsigned short* __restrict__ W1p, const float* __restrict__ b1,
    float* __restrict__ h, unsigned short* __restrict__ hb,
    unsigned short* __restrict__ x0b) {
  const int tid = threadIdx.x;
  const int wv = tid >> 6, lane = tid & 63;
  const int lrow = lane & 15, quad = lane >> 4;
  const int row0 = blockIdx.x * 64;
  const int ar = row0 + wv * 16 + lrow;
  f32x4 acc[8];
#pragma unroll
  for (int t = 0; t < 8; ++t) acc[t] = (f32x4){0.f, 0.f, 0.f, 0.f};

  for (int kk = 0; kk < 16; ++kk) {
    const int kbase = kk * 32 + quad * 8;
    float av[8];
    if (ar < Nn) {
      if (kk < 15) {
        const float4 p0 = *(const float4*)(x + (size_t)ar * DIN + kbase);
        const float4 p1 = *(const float4*)(x + (size_t)ar * DIN + kbase + 4);
        av[0] = p0.x; av[1] = p0.y; av[2] = p0.z; av[3] = p0.w;
        av[4] = p1.x; av[5] = p1.y; av[6] = p1.z; av[7] = p1.w;
      } else {
#pragma unroll
        for (int j = 0; j < 8; ++j)
          av[j] = (kbase + j < DIN) ? x[(size_t)ar * DIN + kbase + j] : 0.f;
      }
    } else {
#pragma unroll
      for (int j = 0; j < 8; ++j) av[j] = 0.f;
    }
    bf16x8 af;
#pragma unroll
    for (int j = 0; j < 8; ++j) af[j] = (short)f2bf(av[j]);
#pragma unroll
    for (int nt = 0; nt < 8; ++nt) {
      const bf16x8 bf = *(const bf16x8*)(W1p + ((size_t)(kk * 4 + quad) * 128 + nt * 16 + lrow) * 8);
      acc[nt] = __builtin_amdgcn_mfma_f32_16x16x32_bf16(af, bf, acc[nt], 0, 0, 0);
    }
  }

  __shared__ float sacc[64 * 132];
#pragma unroll
  for (int nt = 0; nt < 8; ++nt)
#pragma unroll
    for (int i = 0; i < 4; ++i)
      sacc[(wv * 16 + quad * 4 + i) * 132 + nt * 16 + lrow] = acc[nt][i];
  __syncthreads();

  const int row = tid >> 2, cs = (tid & 3) * 32;
  const int gr = row0 + row;
  if (gr < Nn) {
#pragma unroll
    for (int g = 0; g < 4; ++g) {
      const int c0 = cs + g * 8;
      float v[8];
#pragma unroll
      for (int j = 0; j < 8; ++j)
        v[j] = fmaxf(sacc[row * 132 + c0 + j] + b1[c0 + j], 0.f);
      float4 o0 = {v[0], v[1], v[2], v[3]}, o1 = {v[4], v[5], v[6], v[7]};
      *(float4*)(h + (size_t)gr * Hd + c0) = o0;
      *(float4*)(h + (size_t)gr * Hd + c0 + 4) = o1;
      u16x8 ob;
#pragma unroll
      for (int j = 0; j < 8; ++j) ob[j] = f2bf(v[j]);
      *(u16x8*)(hb + (size_t)gr * Hd + c0) = ob;
      *(u16x8*)(x0b + (size_t)gr * Hd + c0) = ob;
    }
  }
}

// ---------------- CSR build ----------------
__global__ void k_hist(const int* __restrict__ rows, int* __restrict__ counts) {
  int e = blockIdx.x * 256 + threadIdx.x;
  if (e < En) atomicAdd(&counts[rows[e]], 1);
}

__global__ __launch_bounds__(1024) void k_scan(const int* __restrict__ counts,
                                               int* __restrict__ ptr) {
  __shared__ int buf[1024];
  __shared__ int s_base;
  const int tid = threadIdx.x;
  if (tid == 0) { s_base = 0; ptr[0] = 0; }
  __syncthreads();
  for (int start = 0; start < Nn; start += 1024) {
    int i = start + tid;
    int v = (i < Nn) ? counts[i] : 0;
    buf[tid] = v;
    __syncthreads();
    for (int off = 1; off < 1024; off <<= 1) {
      int t = (tid >= off) ? buf[tid - off] : 0;
      __syncthreads();
      buf[tid] += t;
      __syncthreads();
    }
    if (i < Nn) ptr[i + 1] = s_base + buf[tid];
    __syncthreads();
    if (tid == 0) s_base += buf[1023];
    __syncthreads();
  }
}

__global__ void k_scatter(const int* __restrict__ rows, const int* __restrict__ cols,
                          const float* __restrict__ w, const int* __restrict__ ptr,
                          int* __restrict__ fill, int* __restrict__ csr_col,
                          float* __restrict__ csr_w) {
  int e = blockIdx.x * 256 + threadIdx.x;
  if (e >= En) return;
  int r = rows[e];
  int pos = atomicAdd(&fill[r], 1);
  int d = ptr[r] + pos;
  csr_col[d] = cols[e];
  csr_w[d] = w[e];
}

// ---------------- SpMM: pb = bf16(0.5 * segment_sum(w * hb[col])) --------------
// One row per wave; edges strided over 4 lane-groups of 16; each lane loads
// uint4 (8 bf16) so a group covers all 128 feats. 2x unroll -> 8 gathers
// in flight per wave. Cross-group combine: shfl_xor 16/32.
__global__ __launch_bounds__(256) void k_spmm(const int* __restrict__ ptr,
    const int* __restrict__ csr_col, const float* __restrict__ csr_w,
    const unsigned short* __restrict__ hb, unsigned short* __restrict__ pb) {
  const int wave = (blockIdx.x * 256 + threadIdx.x) >> 6;
  const int lane = threadIdx.x & 63;
  const int g = lane >> 4;        // edge group 0..3
  const int fl = lane & 15;       // feature lane: feats fl*8 .. fl*8+7
  if (wave >= Nn) return;
  const int s = ptr[wave], e_end = ptr[wave + 1];
  float acc[8];
#pragma unroll
  for (int j = 0; j < 8; ++j) acc[j] = 0.f;

  int e = s + g;
  for (; e + 4 < e_end; e += 8) {
    const int c0 = csr_col[e];
    const int c1 = csr_col[e + 4];
    const float w0 = csr_w[e];
    const float w1 = csr_w[e + 4];
    const uint4 v0 = *(const uint4*)(hb + (size_t)c0 * Hd + fl * 8);
    const uint4 v1 = *(const uint4*)(hb + (size_t)c1 * Hd + fl * 8);
    union { unsigned int i; float f; } t;
    t.i = v0.x << 16;         acc[0] += w0 * t.f;
    t.i = v0.x & 0xFFFF0000u; acc[1] += w0 * t.f;
    t.i = v0.y << 16;         acc[2] += w0 * t.f;
    t.i = v0.y & 0xFFFF0000u; acc[3] += w0 * t.f;
    t.i = v0.z << 16;         acc[4] += w0 * t.f;
    t.i = v0.z & 0xFFFF0000u; acc[5] += w0 * t.f;
    t.i = v0.w << 16;         acc[6] += w0 * t.f;
    t.i = v0.w & 0xFFFF0000u; acc[7] += w0 * t.f;
    t.i = v1.x << 16;         acc[0] += w1 * t.f;
    t.i = v1.x & 0xFFFF0000u; acc[1] += w1 * t.f;
    t.i = v1.y << 16;         acc[2] += w1 * t.f;
    t.i = v1.y & 0xFFFF0000u; acc[3] += w1 * t.f;
    t.i = v1.z << 16;         acc[4] += w1 * t.f;
    t.i = v1.z & 0xFFFF0000u; acc[5] += w1 * t.f;
    t.i = v1.w << 16;         acc[6] += w1 * t.f;
    t.i = v1.w & 0xFFFF0000u; acc[7] += w1 * t.f;
  }
  if (e < e_end) {
    const int c = csr_col[e];
    const float w = csr_w[e];
    const uint4 v = *(const uint4*)(hb + (size_t)c * Hd + fl * 8);
    union { unsigned int i; float f; } t;
    t.i = v.x << 16;         acc[0] += w * t.f;
    t.i = v.x & 0xFFFF0000u; acc[1] += w * t.f;
    t.i = v.y << 16;         acc[2] += w * t.f;
    t.i = v.y & 0xFFFF0000u; acc[3] += w * t.f;
    t.i = v.z << 16;         acc[4] += w * t.f;
    t.i = v.z & 0xFFFF0000u; acc[5] += w * t.f;
    t.i = v.w << 16;         acc[6] += w * t.f;
    t.i = v.w & 0xFFFF0000u; acc[7] += w * t.f;
  }
  // combine the 4 edge groups
#pragma unroll
  for (int j = 0; j < 8; ++j) acc[j] += __shfl_xor(acc[j], 16);
#pragma unroll
  for (int j = 0; j < 8; ++j) acc[j] += __shfl_xor(acc[j], 32);
  if (g == 0) {
    uint4 o;
    o.x = (unsigned int)f2bf(0.5f * acc[0]) | ((unsigned int)f2bf(0.5f * acc[1]) << 16);
    o.y = (unsigned int)f2bf(0.5f * acc[2]) | ((unsigned int)f2bf(0.5f * acc[3]) << 16);
    o.z = (unsigned int)f2bf(0.5f * acc[4]) | ((unsigned int)f2bf(0.5f * acc[5]) << 16);
    o.w = (unsigned int)f2bf(0.5f * acc[6]) | ((unsigned int)f2bf(0.5f * acc[7]) << 16);
    *(uint4*)(pb + (size_t)wave * Hd + fl * 8) = o;
  }
}

// ---------------- layer (MFMA) ----------------
__global__ __launch_bounds__(256) void k_layer(const unsigned short* __restrict__ pb,
    const unsigned short* __restrict__ x0b, const unsigned short* __restrict__ Wcp,
    float* __restrict__ h, unsigned short* __restrict__ hb, float beta) {
  const int tid = threadIdx.x;
  const int wv = tid >> 6, lane = tid & 63;
  const int lrow = lane & 15, quad = lane >> 4;
  const int row0 = blockIdx.x * 64;
  const int ar = row0 + wv * 16 + lrow;
  f32x4 acc[8];
#pragma unroll
  for (int t = 0; t < 8; ++t) acc[t] = (f32x4){0.f, 0.f, 0.f, 0.f};

#pragma unroll
  for (int kk = 0; kk < 8; ++kk) {
    const unsigned short* src = (kk < 4) ? pb : x0b;
    const int ko = (kk & 3) * 32 + quad * 8;
    const bf16x8 af = *(const bf16x8*)(src + (size_t)ar * Hd + ko);
#pragma unroll
    for (int nt = 0; nt < 8; ++nt) {
      const bf16x8 bf = *(const bf16x8*)(Wcp + ((size_t)(kk * 4 + quad) * 128 + nt * 16 + lrow) * 8);
      acc[nt] = __builtin_amdgcn_mfma_f32_16x16x32_bf16(af, bf, acc[nt], 0, 0, 0);
    }
  }

  __shared__ float sacc[64 * 132];
#pragma unroll
  for (int nt = 0; nt < 8; ++nt)
#pragma unroll
    for (int i = 0; i < 4; ++i)
      sacc[(wv * 16 + quad * 4 + i) * 132 + nt * 16 + lrow] = acc[nt][i];
  __syncthreads();

  const int row = tid >> 2, cs = (tid & 3) * 32;
  const int gr = row0 + row;
  if (gr < Nn) {
    const float om = 1.f - beta;
#pragma unroll
    for (int g = 0; g < 4; ++g) {
      const int c0 = cs + g * 8;
      const u16x8 pv = *(const u16x8*)(pb + (size_t)gr * Hd + c0);
      const u16x8 xv = *(const u16x8*)(x0b + (size_t)gr * Hd + c0);
      const float4 h0 = *(const float4*)(h + (size_t)gr * Hd + c0);
      const float4 h1 = *(const float4*)(h + (size_t)gr * Hd + c0 + 4);
      float hv[8] = {h0.x, h0.y, h0.z, h0.w, h1.x, h1.y, h1.z, h1.w};
      float nv[8];
#pragma unroll
      for (int j = 0; j < 8; ++j) {
        const float gemm = sacc[row * 132 + c0 + j];
        const float pj = bf2f(pv[j]);
        const float xj = bf2f(xv[j]);
        const float outv = om * (pj + 0.5f * xj) + beta * gemm;
        nv[j] = fmaxf(hv[j] + outv, 0.f);
      }
      float4 o0 = {nv[0], nv[1], nv[2], nv[3]}, o1 = {nv[4], nv[5], nv[6], nv[7]};
      *(float4*)(h + (size_t)gr * Hd + c0) = o0;
      *(float4*)(h + (size_t)gr * Hd + c0 + 4) = o1;
      u16x8 ob;
#pragma unroll
      for (int j = 0; j < 8; ++j) ob[j] = f2bf(nv[j]);
      *(u16x8*)(hb + (size_t)gr * Hd + c0) = ob;
    }
  }
}

// ---------------- head ----------------
__global__ __launch_bounds__(256) void k_head(const float* __restrict__ h,
    const float* __restrict__ W2, const float* __restrict__ b2,
    unsigned short* __restrict__ anb, float* __restrict__ p_lc,
    float* __restrict__ out_emb) {
  const int wid = (blockIdx.x * 256 + threadIdx.x) >> 6;
  const int lane = threadIdx.x & 63;
  if (wid >= Bb) return;
  const float* hr = h + (size_t)wid * Hd;
  const float v0 = hr[lane], v1 = hr[lane + 64];
  out_emb[wid * Hd + lane] = v0;
  out_emb[wid * Hd + lane + 64] = v1;
  float ss = v0 * v0 + v1 * v1;
#pragma unroll
  for (int off = 32; off > 0; off >>= 1) ss += __shfl_xor(ss, off);
  const float inv = 1.f / fmaxf(sqrtf(ss), 1e-8f);
  anb[wid * Hd + lane] = f2bf(v0 * inv);
  anb[wid * Hd + lane + 64] = f2bf(v1 * inv);
  float l = 0.f;
  if (lane < Cc) {
    for (int k = 0; k < Hd; ++k) l += hr[k] * W2[k * Cc + lane];
    l += b2[lane];
  }
  float lm = (lane < Cc) ? l : -3.0e38f;
#pragma unroll
  for (int off = 32; off > 0; off >>= 1) lm = fmaxf(lm, __shfl_xor(lm, off));
  float ex = (lane < Cc) ? expf(l - lm) : 0.f;
#pragma unroll
  for (int off = 32; off > 0; off >>= 1) ex += __shfl_xor(ex, off);
  const float lse = logf(ex);
  if (lane < Cc) p_lc[wid * Cc + lane] = l - lm - lse;
}

// ---------------- fused sim = an@an^T (bf16 MFMA) with running top-5 ----------
// Round-2 measured-best structure: 256 thr, CH_N=4, ungated per-(sub,i) insert.
#define CH_N  4
#define CH_SZ 2500
#define SB_LD 136
__global__ __launch_bounds__(256) void k_simtopk(const unsigned short* __restrict__ anb,
    float* __restrict__ cval, int* __restrict__ cidx) {
  __shared__ __align__(16) char smem[40960];
  unsigned short* sb = (unsigned short*)smem;
  const int rt = blockIdx.x / CH_N;
  const int chunk = blockIdx.x % CH_N;
  const int row0 = rt * 64;
  const int cbeg = chunk * CH_SZ;
  const int cend = cbeg + CH_SZ;
  const int tid = threadIdx.x;
  const int wv = tid >> 6;
  const int lane = tid & 63;
  const int lrow = lane & 15;
  const int quad = lane >> 4;

  union Frag { uint4 u4; bf16x8 v; };
  bf16x8 afr[4];
  const int ar = row0 + wv * 16 + lrow;
#pragma unroll
  for (int kq = 0; kq < 4; ++kq) {
    Frag f;
    f.u4 = make_uint4(0u, 0u, 0u, 0u);
    if (ar < Bb) f.u4 = *(const uint4*)(anb + (size_t)ar * Hd + kq * 32 + quad * 8);
    afr[kq] = f.v;
  }

  float bv[4][KT];
  int bi[4][KT];
#pragma unroll
  for (int r = 0; r < 4; ++r)
#pragma unroll
    for (int t = 0; t < KT; ++t) { bv[r][t] = -3.0e38f; bi[r][t] = 0x7fffffff; }

  const int ntile = (CH_SZ + 63) / 64;
  for (int t = 0; t < ntile; ++t) {
    const int c0 = cbeg + t * 64;
    __syncthreads();
    for (int i = tid; i < 1024; i += 256) {
      const int r = i >> 4, ch = i & 15;
      const int gc = c0 + r;
      uint4 v = make_uint4(0u, 0u, 0u, 0u);
      if (gc < cend) v = *(const uint4*)(anb + (size_t)gc * Hd + ch * 8);
      *(uint4*)&sb[r * SB_LD + ch * 8] = v;
    }
    __syncthreads();
#pragma unroll
    for (int sub = 0; sub < 4; ++sub) {
      f32x4 acc = {0.f, 0.f, 0.f, 0.f};
      const int scol = sub * 16 + lrow;
#pragma unroll
      for (int kq = 0; kq < 4; ++kq) {
        bf16x8 bfr = *(const bf16x8*)&sb[scol * SB_LD + kq * 32 + quad * 8];
        acc = __builtin_amdgcn_mfma_f32_16x16x32_bf16(afr[kq], bfr, acc, 0, 0, 0);
      }
      const int gc = c0 + scol;
      const bool ok = gc < cend;
#pragma unroll
      for (int i = 0; i < 4; ++i) {
        const float v = ok ? acc[i] : -3.0e38f;
        if (v > bv[i][KT - 1]) {
          float tv = v; int ti = gc;
#pragma unroll
          for (int s = 0; s < KT; ++s) {
            if (tv > bv[i][s]) {
              float ov = bv[i][s]; int oi = bi[i][s];
              bv[i][s] = tv; bi[i][s] = ti; tv = ov; ti = oi;
            }
          }
        }
      }
    }
  }

  __syncthreads();
  float* mv = (float*)smem;
  int* mi = (int*)(smem + 20480);
#pragma unroll
  for (int i = 0; i < 4; ++i) {
    const int row = wv * 16 + quad * 4 + i;
#pragma unroll
    for (int t = 0; t < KT; ++t) {
      mv[row * 80 + lrow * KT + t] = bv[i][t];
      mi[row * 80 + lrow * KT + t] = bi[i][t];
    }
  }
  __syncthreads();
  if (tid < 64) {
    const int gr = row0 + tid;
    if (gr < Bb) {
      float tv5[KT]; int ti5[KT];
#pragma unroll
      for (int t = 0; t < KT; ++t) { tv5[t] = -3.0e38f; ti5[t] = 0x7fffffff; }
      for (int m = 0; m < 80; ++m) {
        float v = mv[tid * 80 + m]; int id = mi[tid * 80 + m];
        if (v > tv5[KT - 1] || (v == tv5[KT - 1] && id < ti5[KT - 1])) {
#pragma unroll
          for (int s = 0; s < KT; ++s) {
            if (v > tv5[s] || (v == tv5[s] && id < ti5[s])) {
              float ov = tv5[s]; int oi = ti5[s];
              tv5[s] = v; ti5[s] = id; v = ov; id = oi;
            }
          }
        }
      }
#pragma unroll
      for (int t = 0; t < KT; ++t) {
        cval[gr * (CH_N * KT) + chunk * KT + t] = tv5[t];
        cidx[gr * (CH_N * KT) + chunk * KT + t] = ti5[t];
      }
    }
  }
}

// ---------------- final ----------------
__global__ __launch_bounds__(256) void k_final(const float* __restrict__ cval,
    const int* __restrict__ cidx, const int* __restrict__ y,
    const float* __restrict__ p_lc, float* __restrict__ out_final) {
  const int b = blockIdx.x * 256 + threadIdx.x;
  if (b >= Bb) return;
  float tv5[KT]; int ti5[KT];
#pragma unroll
  for (int t = 0; t < KT; ++t) { tv5[t] = -3.0e38f; ti5[t] = 0x7fffffff; }
#pragma unroll
  for (int m = 0; m < CH_N * KT; ++m) {
    float v = cval[b * (CH_N * KT) + m]; int id = cidx[b * (CH_N * KT) + m];
    if (v > tv5[KT - 1] || (v == tv5[KT - 1] && id < ti5[KT - 1])) {
#pragma unroll
      for (int t = 0; t < KT; ++t) {
        if (v > tv5[t] || (v == tv5[t] && id < ti5[t])) {
          float ov = tv5[t]; int oi = ti5[t];
          tv5[t] = v; ti5[t] = id; v = ov; id = oi;
        }
      }
    }
  }
  float w[KT]; int cls[KT];
#pragma unroll
  for (int t = 0; t < KT; ++t) { w[t] = expf(tv5[t]); cls[t] = y[ti5[t]]; }
  float m = -3.0e38f;
  for (int c = 0; c < Cc; ++c) {
    float f = 0.f;
#pragma unroll
    for (int t = 0; t < KT; ++t) f += (cls[t] == c) ? w[t] : 0.f;
    m = fmaxf(m, f);
  }
  float s = 0.f;
  for (int c = 0; c < Cc; ++c) {
    float f = 0.f;
#pragma unroll
    for (int t = 0; t < KT; ++t) f += (cls[t] == c) ? w[t] : 0.f;
    s += expf(f - m);
  }
  const float lse = logf(s);
  for (int c = 0; c < Cc; ++c) {
    float f = 0.f;
#pragma unroll
    for (int t = 0; t < KT; ++t) f += (cls[t] == c) ? w[t] : 0.f;
    out_final[b * Cc + c] = 0.5f * p_lc[b * Cc + c] + 0.5f * (f - m - lse);
  }
}

extern "C" void kernel_launch(void* const* d_in, const int* in_sizes, int n_in,
                              void* d_out, int out_size, void* d_ws, size_t ws_size,
                              hipStream_t stream) {
  const float* x  = (const float*)d_in[0];
  const int* erow = (const int*)d_in[1];
  const int* ecol = erow + En;
  const float* ew = (const float*)d_in[2];
  const int* y    = (const int*)d_in[3];
  const float* W1 = (const float*)d_in[5];
  const float* b1 = (const float*)d_in[6];
  const float* cw1 = (const float*)d_in[7];
  const float* cw2 = (const float*)d_in[8];
  const float* W2 = (const float*)d_in[9];
  const float* b2 = (const float*)d_in[10];
  float* out = (float*)d_out;

  float* ws = (float*)d_ws;
  size_t off = 0;
  float* h   = ws + off; off += (size_t)NR * Hd;
  float* plc = ws + off; off += (size_t)Bb * Cc;
  float* cval = ws + off; off += (size_t)Bb * (CH_N * KT);
  int* cidx  = (int*)(ws + off); off += (size_t)Bb * (CH_N * KT);
  int* counts = (int*)(ws + off); off += Nn;
  int* fill   = (int*)(ws + off); off += Nn;
  int* rptr   = (int*)(ws + off); off += Nn + 4;
  int* ccol   = (int*)(ws + off); off += En;
  float* cwt  = ws + off; off += En;
  unsigned short* anb = (unsigned short*)(ws + off); off += (size_t)Bb * Hd / 2;
  unsigned short* hb  = (unsigned short*)(ws + off); off += (size_t)NR * Hd / 2;
  unsigned short* x0b = (unsigned short*)(ws + off); off += (size_t)NR * Hd / 2;
  unsigned short* pb  = (unsigned short*)(ws + off); off += (size_t)NR * Hd / 2;
  unsigned short* W1p = (unsigned short*)(ws + off); off += 65536 / 2;
  unsigned short* Wcp = (unsigned short*)(ws + off); off += 294912 / 2;

  k_pack_w1<<<256, 256, 0, stream>>>(W1, W1p);
  k_pack_wc<<<1152, 256, 0, stream>>>(cw1, cw2, Wcp);
  k_in<<<NR / 64, 256, 0, stream>>>(x, W1p, b1, h, hb, x0b);
  hipMemsetAsync(counts, 0, (size_t)2 * Nn * sizeof(int), stream);
  k_hist<<<(En + 255) / 256, 256, 0, stream>>>(erow, counts);
  k_scan<<<1, 1024, 0, stream>>>(counts, rptr);
  k_scatter<<<(En + 255) / 256, 256, 0, stream>>>(erow, ecol, ew, rptr, fill, ccol, cwt);
  for (int l = 0; l < Ll; ++l) {
    const float beta = logf(1.0f / (float)(l + 1) + 1.0f);
    k_spmm<<<(Nn * 64 + 255) / 256, 256, 0, stream>>>(rptr, ccol, cwt, hb, pb);
    k_layer<<<NR / 64, 256, 0, stream>>>(pb, x0b, Wcp + (size_t)l * 32768, h, hb, beta);
  }
  k_head<<<(Bb * 64) / 256, 256, 0, stream>>>(h, W2, b2, anb, plc, out + (size_t)Bb * Cc);
  k_simtopk<<<((Bb + 63) / 64) * CH_N, 256, 0, stream>>>(anb, cval, cidx);
  k_final<<<(Bb + 255) / 256, 256, 0, stream>>>(cval, cidx, y, plc, out);
}

// Round 8
// 1194.821 us; speedup vs baseline: 2.7159x; 1.0027x over previous
//
#include <hip/hip_runtime.h>
#include <hip/hip_bf16.h>
#include <math.h>

#define Nn  50000
#define NR  50048   // rows padded to 64
#define En  800000
#define DIN 500
#define Hd  128
#define Cc  40
#define Bb  10000
#define Ll  9
#define KT  5

typedef short bf16x8 __attribute__((ext_vector_type(8)));
typedef unsigned short u16x8 __attribute__((ext_vector_type(8)));
typedef float f32x4 __attribute__((ext_vector_type(4)));

__device__ inline float bf2f(unsigned short u) {
  union { unsigned int i; float f; } c; c.i = (unsigned int)u << 16; return c.f;
}
__device__ inline unsigned short f2bf(float f) {
  __hip_bfloat16 b = __float2bfloat16(f);
  return *(unsigned short*)&b;
}

// ---------------- weight packing into B-fragment layout ----------------
__global__ __launch_bounds__(256) void k_pack_w1(const float* __restrict__ W1,
                                                 unsigned short* __restrict__ W1p) {
  const int id = blockIdx.x * 256 + threadIdx.x;   // 16*4*128*8 = 65536
  if (id >= 65536) return;
  const int j = id & 7, col = (id >> 3) & 127, qk = id >> 10;  // qk = kk*4+quad
  const int k = (qk >> 2) * 32 + (qk & 3) * 8 + j;
  W1p[id] = f2bf((k < DIN) ? W1[(size_t)k * Hd + col] : 0.f);
}

// Wcat[l] = [W1l ; 0.5*W2l]  (K=256), same frag packing, 32768 elems/layer
__global__ __launch_bounds__(256) void k_pack_wc(const float* __restrict__ cw1,
    const float* __restrict__ cw2, unsigned short* __restrict__ Wcp) {
  const int id = blockIdx.x * 256 + threadIdx.x;   // 9*32768 = 294912
  if (id >= 294912) return;
  const int j = id & 7, col = (id >> 3) & 127, qk = (id >> 10) & 31, l = id >> 15;
  const int k = (qk >> 2) * 32 + (qk & 3) * 8 + j;  // 0..255
  float v;
  if (k < 128) v = cw1[((size_t)l * 128 + k) * 128 + col];
  else         v = 0.5f * cw2[((size_t)l * 128 + (k - 128)) * 128 + col];
  Wcp[id] = f2bf(v);
}

// ---------------- input GEMM (MFMA): h = relu(x @ W1 + b1) ----------------
__global__ __launch_bounds__(256) void k_in(const float* __restrict__ x,
    const unsigned short* __restrict__ W1p, const float* __restrict__ b1,
    float* __restrict__ h, unsigned short* __restrict__ hb,
    unsigned short* __restrict__ x0b) {
  const int tid = threadIdx.x;
  const int wv = tid >> 6, lane = tid & 63;
  const int lrow = lane & 15, quad = lane >> 4;
  const int row0 = blockIdx.x * 64;
  const int ar = row0 + wv * 16 + lrow;
  f32x4 acc[8];
#pragma unroll
  for (int t = 0; t < 8; ++t) acc[t] = (f32x4){0.f, 0.f, 0.f, 0.f};

  for (int kk = 0; kk < 16; ++kk) {
    const int kbase = kk * 32 + quad * 8;
    float av[8];
    if (ar < Nn) {
      if (kk < 15) {
        const float4 p0 = *(const float4*)(x + (size_t)ar * DIN + kbase);
        const float4 p1 = *(const float4*)(x + (size_t)ar * DIN + kbase + 4);
        av[0] = p0.x; av[1] = p0.y; av[2] = p0.z; av[3] = p0.w;
        av[4] = p1.x; av[5] = p1.y; av[6] = p1.z; av[7] = p1.w;
      } else {
#pragma unroll
        for (int j = 0; j < 8; ++j)
          av[j] = (kbase + j < DIN) ? x[(size_t)ar * DIN + kbase + j] : 0.f;
      }
    } else {
#pragma unroll
      for (int j = 0; j < 8; ++j) av[j] = 0.f;
    }
    bf16x8 af;
#pragma unroll
    for (int j = 0; j < 8; ++j) af[j] = (short)f2bf(av[j]);
#pragma unroll
    for (int nt = 0; nt < 8; ++nt) {
      const bf16x8 bf = *(const bf16x8*)(W1p + ((size_t)(kk * 4 + quad) * 128 + nt * 16 + lrow) * 8);
      acc[nt] = __builtin_amdgcn_mfma_f32_16x16x32_bf16(af, bf, acc[nt], 0, 0, 0);
    }
  }

  __shared__ float sacc[64 * 132];
#pragma unroll
  for (int nt = 0; nt < 8; ++nt)
#pragma unroll
    for (int i = 0; i < 4; ++i)
      sacc[(wv * 16 + quad * 4 + i) * 132 + nt * 16 + lrow] = acc[nt][i];
  __syncthreads();

  const int row = tid >> 2, cs = (tid & 3) * 32;
  const int gr = row0 + row;
  if (gr < Nn) {
#pragma unroll
    for (int g = 0; g < 4; ++g) {
      const int c0 = cs + g * 8;
      float v[8];
#pragma unroll
      for (int j = 0; j < 8; ++j)
        v[j] = fmaxf(sacc[row * 132 + c0 + j] + b1[c0 + j], 0.f);
      float4 o0 = {v[0], v[1], v[2], v[3]}, o1 = {v[4], v[5], v[6], v[7]};
      *(float4*)(h + (size_t)gr * Hd + c0) = o0;
      *(float4*)(h + (size_t)gr * Hd + c0 + 4) = o1;
      u16x8 ob;
#pragma unroll
      for (int j = 0; j < 8; ++j) ob[j] = f2bf(v[j]);
      *(u16x8*)(hb + (size_t)gr * Hd + c0) = ob;
      *(u16x8*)(x0b + (size_t)gr * Hd + c0) = ob;
    }
  }
}

// ---------------- CSR build ----------------
__global__ void k_hist(const int* __restrict__ rows, int* __restrict__ counts) {
  int e = blockIdx.x * 256 + threadIdx.x;
  if (e < En) atomicAdd(&counts[rows[e]], 1);
}

__global__ __launch_bounds__(1024) void k_scan(const int* __restrict__ counts,
                                               int* __restrict__ ptr) {
  __shared__ int buf[1024];
  __shared__ int s_base;
  const int tid = threadIdx.x;
  if (tid == 0) { s_base = 0; ptr[0] = 0; }
  __syncthreads();
  for (int start = 0; start < Nn; start += 1024) {
    int i = start + tid;
    int v = (i < Nn) ? counts[i] : 0;
    buf[tid] = v;
    __syncthreads();
    for (int off = 1; off < 1024; off <<= 1) {
      int t = (tid >= off) ? buf[tid - off] : 0;
      __syncthreads();
      buf[tid] += t;
      __syncthreads();
    }
    if (i < Nn) ptr[i + 1] = s_base + buf[tid];
    __syncthreads();
    if (tid == 0) s_base += buf[1023];
    __syncthreads();
  }
}

__global__ void k_scatter(const int* __restrict__ rows, const int* __restrict__ cols,
                          const float* __restrict__ w, const int* __restrict__ ptr,
                          int* __restrict__ fill, int* __restrict__ csr_col,
                          float* __restrict__ csr_w) {
  int e = blockIdx.x * 256 + threadIdx.x;
  if (e >= En) return;
  int r = rows[e];
  int pos = atomicAdd(&fill[r], 1);
  int d = ptr[r] + pos;
  csr_col[d] = cols[e];
  csr_w[d] = w[e];
}

// ---------------- SpMM: pb = bf16(0.5 * segment_sum(w * hb[col])) --------------
// One row per wave; edges strided over 4 lane-groups of 16; each lane loads
// uint4 (8 bf16). x4-deep unroll -> up to 16 gathers in flight per wave.
// Coverage per group g (indices == g mod 4): x4 loop takes e..e+12 while
// e+12<end; x2 loop takes e,e+4 while e+4<end; tail takes lone e. Disjoint+complete.
__global__ __launch_bounds__(256) void k_spmm(const int* __restrict__ ptr,
    const int* __restrict__ csr_col, const float* __restrict__ csr_w,
    const unsigned short* __restrict__ hb, unsigned short* __restrict__ pb) {
  const int wave = (blockIdx.x * 256 + threadIdx.x) >> 6;
  const int lane = threadIdx.x & 63;
  const int g = lane >> 4;        // edge group 0..3
  const int fl = lane & 15;       // feature lane: feats fl*8 .. fl*8+7
  if (wave >= Nn) return;
  const int s = ptr[wave], e_end = ptr[wave + 1];
  float acc[8];
#pragma unroll
  for (int j = 0; j < 8; ++j) acc[j] = 0.f;

  auto acc8 = [&](uint4 v, float w) {
    union { unsigned int i; float f; } t;
    t.i = v.x << 16;         acc[0] += w * t.f;
    t.i = v.x & 0xFFFF0000u; acc[1] += w * t.f;
    t.i = v.y << 16;         acc[2] += w * t.f;
    t.i = v.y & 0xFFFF0000u; acc[3] += w * t.f;
    t.i = v.z << 16;         acc[4] += w * t.f;
    t.i = v.z & 0xFFFF0000u; acc[5] += w * t.f;
    t.i = v.w << 16;         acc[6] += w * t.f;
    t.i = v.w & 0xFFFF0000u; acc[7] += w * t.f;
  };

  int e = s + g;
  for (; e + 12 < e_end; e += 16) {        // 4 edges per group in flight
    const int c0 = csr_col[e];
    const int c1 = csr_col[e + 4];
    const int c2 = csr_col[e + 8];
    const int c3 = csr_col[e + 12];
    const float w0 = csr_w[e];
    const float w1 = csr_w[e + 4];
    const float w2 = csr_w[e + 8];
    const float w3 = csr_w[e + 12];
    const uint4 v0 = *(const uint4*)(hb + (size_t)c0 * Hd + fl * 8);
    const uint4 v1 = *(const uint4*)(hb + (size_t)c1 * Hd + fl * 8);
    const uint4 v2 = *(const uint4*)(hb + (size_t)c2 * Hd + fl * 8);
    const uint4 v3 = *(const uint4*)(hb + (size_t)c3 * Hd + fl * 8);
    acc8(v0, w0); acc8(v1, w1); acc8(v2, w2); acc8(v3, w3);
  }
  for (; e + 4 < e_end; e += 8) {          // 2 edges per group
    const int c0 = csr_col[e];
    const int c1 = csr_col[e + 4];
    const float w0 = csr_w[e];
    const float w1 = csr_w[e + 4];
    const uint4 v0 = *(const uint4*)(hb + (size_t)c0 * Hd + fl * 8);
    const uint4 v1 = *(const uint4*)(hb + (size_t)c1 * Hd + fl * 8);
    acc8(v0, w0); acc8(v1, w1);
  }
  if (e < e_end) {
    const int c = csr_col[e];
    const float w = csr_w[e];
    const uint4 v = *(const uint4*)(hb + (size_t)c * Hd + fl * 8);
    acc8(v, w);
  }
  // combine the 4 edge groups
#pragma unroll
  for (int j = 0; j < 8; ++j) acc[j] += __shfl_xor(acc[j], 16);
#pragma unroll
  for (int j = 0; j < 8; ++j) acc[j] += __shfl_xor(acc[j], 32);
  if (g == 0) {
    uint4 o;
    o.x = (unsigned int)f2bf(0.5f * acc[0]) | ((unsigned int)f2bf(0.5f * acc[1]) << 16);
    o.y = (unsigned int)f2bf(0.5f * acc[2]) | ((unsigned int)f2bf(0.5f * acc[3]) << 16);
    o.z = (unsigned int)f2bf(0.5f * acc[4]) | ((unsigned int)f2bf(0.5f * acc[5]) << 16);
    o.w = (unsigned int)f2bf(0.5f * acc[6]) | ((unsigned int)f2bf(0.5f * acc[7]) << 16);
    *(uint4*)(pb + (size_t)wave * Hd + fl * 8) = o;
  }
}

// ---------------- layer (MFMA) ----------------
__global__ __launch_bounds__(256) void k_layer(const unsigned short* __restrict__ pb,
    const unsigned short* __restrict__ x0b, const unsigned short* __restrict__ Wcp,
    float* __restrict__ h, unsigned short* __restrict__ hb, float beta) {
  const int tid = threadIdx.x;
  const int wv = tid >> 6, lane = tid & 63;
  const int lrow = lane & 15, quad = lane >> 4;
  const int row0 = blockIdx.x * 64;
  const int ar = row0 + wv * 16 + lrow;
  f32x4 acc[8];
#pragma unroll
  for (int t = 0; t < 8; ++t) acc[t] = (f32x4){0.f, 0.f, 0.f, 0.f};

#pragma unroll
  for (int kk = 0; kk < 8; ++kk) {
    const unsigned short* src = (kk < 4) ? pb : x0b;
    const int ko = (kk & 3) * 32 + quad * 8;
    const bf16x8 af = *(const bf16x8*)(src + (size_t)ar * Hd + ko);
#pragma unroll
    for (int nt = 0; nt < 8; ++nt) {
      const bf16x8 bf = *(const bf16x8*)(Wcp + ((size_t)(kk * 4 + quad) * 128 + nt * 16 + lrow) * 8);
      acc[nt] = __builtin_amdgcn_mfma_f32_16x16x32_bf16(af, bf, acc[nt], 0, 0, 0);
    }
  }

  __shared__ float sacc[64 * 132];
#pragma unroll
  for (int nt = 0; nt < 8; ++nt)
#pragma unroll
    for (int i = 0; i < 4; ++i)
      sacc[(wv * 16 + quad * 4 + i) * 132 + nt * 16 + lrow] = acc[nt][i];
  __syncthreads();

  const int row = tid >> 2, cs = (tid & 3) * 32;
  const int gr = row0 + row;
  if (gr < Nn) {
    const float om = 1.f - beta;
#pragma unroll
    for (int g = 0; g < 4; ++g) {
      const int c0 = cs + g * 8;
      const u16x8 pv = *(const u16x8*)(pb + (size_t)gr * Hd + c0);
      const u16x8 xv = *(const u16x8*)(x0b + (size_t)gr * Hd + c0);
      const float4 h0 = *(const float4*)(h + (size_t)gr * Hd + c0);
      const float4 h1 = *(const float4*)(h + (size_t)gr * Hd + c0 + 4);
      float hv[8] = {h0.x, h0.y, h0.z, h0.w, h1.x, h1.y, h1.z, h1.w};
      float nv[8];
#pragma unroll
      for (int j = 0; j < 8; ++j) {
        const float gemm = sacc[row * 132 + c0 + j];
        const float pj = bf2f(pv[j]);
        const float xj = bf2f(xv[j]);
        const float outv = om * (pj + 0.5f * xj) + beta * gemm;
        nv[j] = fmaxf(hv[j] + outv, 0.f);
      }
      float4 o0 = {nv[0], nv[1], nv[2], nv[3]}, o1 = {nv[4], nv[5], nv[6], nv[7]};
      *(float4*)(h + (size_t)gr * Hd + c0) = o0;
      *(float4*)(h + (size_t)gr * Hd + c0 + 4) = o1;
      u16x8 ob;
#pragma unroll
      for (int j = 0; j < 8; ++j) ob[j] = f2bf(nv[j]);
      *(u16x8*)(hb + (size_t)gr * Hd + c0) = ob;
    }
  }
}

// ---------------- head ----------------
__global__ __launch_bounds__(256) void k_head(const float* __restrict__ h,
    const float* __restrict__ W2, const float* __restrict__ b2,
    unsigned short* __restrict__ anb, float* __restrict__ p_lc,
    float* __restrict__ out_emb) {
  const int wid = (blockIdx.x * 256 + threadIdx.x) >> 6;
  const int lane = threadIdx.x & 63;
  if (wid >= Bb) return;
  const float* hr = h + (size_t)wid * Hd;
  const float v0 = hr[lane], v1 = hr[lane + 64];
  out_emb[wid * Hd + lane] = v0;
  out_emb[wid * Hd + lane + 64] = v1;
  float ss = v0 * v0 + v1 * v1;
#pragma unroll
  for (int off = 32; off > 0; off >>= 1) ss += __shfl_xor(ss, off);
  const float inv = 1.f / fmaxf(sqrtf(ss), 1e-8f);
  anb[wid * Hd + lane] = f2bf(v0 * inv);
  anb[wid * Hd + lane + 64] = f2bf(v1 * inv);
  float l = 0.f;
  if (lane < Cc) {
    for (int k = 0; k < Hd; ++k) l += hr[k] * W2[k * Cc + lane];
    l += b2[lane];
  }
  float lm = (lane < Cc) ? l : -3.0e38f;
#pragma unroll
  for (int off = 32; off > 0; off >>= 1) lm = fmaxf(lm, __shfl_xor(lm, off));
  float ex = (lane < Cc) ? expf(l - lm) : 0.f;
#pragma unroll
  for (int off = 32; off > 0; off >>= 1) ex += __shfl_xor(ex, off);
  const float lse = logf(ex);
  if (lane < Cc) p_lc[wid * Cc + lane] = l - lm - lse;
}

// ---------------- fused sim = an@an^T (bf16 MFMA) with running top-5 ----------
// Round-2 measured-best structure: 256 thr, CH_N=4, guarded everywhere.
// (Guard-free full tiles NaN'd in r5/r6 despite an in-bounds proof — do not retry.)
#define CH_N  4
#define CH_SZ 2500
#define SB_LD 136
__global__ __launch_bounds__(256) void k_simtopk(const unsigned short* __restrict__ anb,
    float* __restrict__ cval, int* __restrict__ cidx) {
  __shared__ __align__(16) char smem[40960];
  unsigned short* sb = (unsigned short*)smem;
  const int rt = blockIdx.x / CH_N;
  const int chunk = blockIdx.x % CH_N;
  const int row0 = rt * 64;
  const int cbeg = chunk * CH_SZ;
  const int cend = cbeg + CH_SZ;
  const int tid = threadIdx.x;
  const int wv = tid >> 6;
  const int lane = tid & 63;
  const int lrow = lane & 15;
  const int quad = lane >> 4;

  union Frag { uint4 u4; bf16x8 v; };
  bf16x8 afr[4];
  const int ar = row0 + wv * 16 + lrow;
#pragma unroll
  for (int kq = 0; kq < 4; ++kq) {
    Frag f;
    f.u4 = make_uint4(0u, 0u, 0u, 0u);
    if (ar < Bb) f.u4 = *(const uint4*)(anb + (size_t)ar * Hd + kq * 32 + quad * 8);
    afr[kq] = f.v;
  }

  float bv[4][KT];
  int bi[4][KT];
#pragma unroll
  for (int r = 0; r < 4; ++r)
#pragma unroll
    for (int t = 0; t < KT; ++t) { bv[r][t] = -3.0e38f; bi[r][t] = 0x7fffffff; }

  const int ntile = (CH_SZ + 63) / 64;
  for (int t = 0; t < ntile; ++t) {
    const int c0 = cbeg + t * 64;
    __syncthreads();
    for (int i = tid; i < 1024; i += 256) {
      const int r = i >> 4, ch = i & 15;
      const int gc = c0 + r;
      uint4 v = make_uint4(0u, 0u, 0u, 0u);
      if (gc < cend) v = *(const uint4*)(anb + (size_t)gc * Hd + ch * 8);
      *(uint4*)&sb[r * SB_LD + ch * 8] = v;
    }
    __syncthreads();
#pragma unroll
    for (int sub = 0; sub < 4; ++sub) {
      f32x4 acc = {0.f, 0.f, 0.f, 0.f};
      const int scol = sub * 16 + lrow;
#pragma unroll
      for (int kq = 0; kq < 4; ++kq) {
        bf16x8 bfr = *(const bf16x8*)&sb[scol * SB_LD + kq * 32 + quad * 8];
        acc = __builtin_amdgcn_mfma_f32_16x16x32_bf16(afr[kq], bfr, acc, 0, 0, 0);
      }
      const int gc = c0 + scol;
      const bool ok = gc < cend;
#pragma unroll
      for (int i = 0; i < 4; ++i) {
        const float v = ok ? acc[i] : -3.0e38f;
        if (v > bv[i][KT - 1]) {
          float tv = v; int ti = gc;
#pragma unroll
          for (int s = 0; s < KT; ++s) {
            if (tv > bv[i][s]) {
              float ov = bv[i][s]; int oi = bi[i][s];
              bv[i][s] = tv; bi[i][s] = ti; tv = ov; ti = oi;
            }
          }
        }
      }
    }
  }

  __syncthreads();
  float* mv = (float*)smem;
  int* mi = (int*)(smem + 20480);
#pragma unroll
  for (int i = 0; i < 4; ++i) {
    const int row = wv * 16 + quad * 4 + i;
#pragma unroll
    for (int t = 0; t < KT; ++t) {
      mv[row * 80 + lrow * KT + t] = bv[i][t];
      mi[row * 80 + lrow * KT + t] = bi[i][t];
    }
  }
  __syncthreads();
  if (tid < 64) {
    const int gr = row0 + tid;
    if (gr < Bb) {
      float tv5[KT]; int ti5[KT];
#pragma unroll
      for (int t = 0; t < KT; ++t) { tv5[t] = -3.0e38f; ti5[t] = 0x7fffffff; }
      for (int m = 0; m < 80; ++m) {
        float v = mv[tid * 80 + m]; int id = mi[tid * 80 + m];
        if (v > tv5[KT - 1] || (v == tv5[KT - 1] && id < ti5[KT - 1])) {
#pragma unroll
          for (int s = 0; s < KT; ++s) {
            if (v > tv5[s] || (v == tv5[s] && id < ti5[s])) {
              float ov = tv5[s]; int oi = ti5[s];
              tv5[s] = v; ti5[s] = id; v = ov; id = oi;
            }
          }
        }
      }
#pragma unroll
      for (int t = 0; t < KT; ++t) {
        cval[gr * (CH_N * KT) + chunk * KT + t] = tv5[t];
        cidx[gr * (CH_N * KT) + chunk * KT + t] = ti5[t];
      }
    }
  }
}

// ---------------- final ----------------
__global__ __launch_bounds__(256) void k_final(const float* __restrict__ cval,
    const int* __restrict__ cidx, const int* __restrict__ y,
    const float* __restrict__ p_lc, float* __restrict__ out_final) {
  const int b = blockIdx.x * 256 + threadIdx.x;
  if (b >= Bb) return;
  float tv5[KT]; int ti5[KT];
#pragma unroll
  for (int t = 0; t < KT; ++t) { tv5[t] = -3.0e38f; ti5[t] = 0x7fffffff; }
#pragma unroll
  for (int m = 0; m < CH_N * KT; ++m) {
    float v = cval[b * (CH_N * KT) + m]; int id = cidx[b * (CH_N * KT) + m];
    if (v > tv5[KT - 1] || (v == tv5[KT - 1] && id < ti5[KT - 1])) {
#pragma unroll
      for (int t = 0; t < KT; ++t) {
        if (v > tv5[t] || (v == tv5[t] && id < ti5[t])) {
          float ov = tv5[t]; int oi = ti5[t];
          tv5[t] = v; ti5[t] = id; v = ov; id = oi;
        }
      }
    }
  }
  float w[KT]; int cls[KT];
#pragma unroll
  for (int t = 0; t < KT; ++t) { w[t] = expf(tv5[t]); cls[t] = y[ti5[t]]; }
  float m = -3.0e38f;
  for (int c = 0; c < Cc; ++c) {
    float f = 0.f;
#pragma unroll
    for (int t = 0; t < KT; ++t) f += (cls[t] == c) ? w[t] : 0.f;
    m = fmaxf(m, f);
  }
  float s = 0.f;
  for (int c = 0; c < Cc; ++c) {
    float f = 0.f;
#pragma unroll
    for (int t = 0; t < KT; ++t) f += (cls[t] == c) ? w[t] : 0.f;
    s += expf(f - m);
  }
  const float lse = logf(s);
  for (int c = 0; c < Cc; ++c) {
    float f = 0.f;
#pragma unroll
    for (int t = 0; t < KT; ++t) f += (cls[t] == c) ? w[t] : 0.f;
    out_final[b * Cc + c] = 0.5f * p_lc[b * Cc + c] + 0.5f * (f - m - lse);
  }
}

extern "C" void kernel_launch(void* const* d_in, const int* in_sizes, int n_in,
                              void* d_out, int out_size, void* d_ws, size_t ws_size,
                              hipStream_t stream) {
  const float* x  = (const float*)d_in[0];
  const int* erow = (const int*)d_in[1];
  const int* ecol = erow + En;
  const float* ew = (const float*)d_in[2];
  const int* y    = (const int*)d_in[3];
  const float* W1 = (const float*)d_in[5];
  const float* b1 = (const float*)d_in[6];
  const float* cw1 = (const float*)d_in[7];
  const float* cw2 = (const float*)d_in[8];
  const float* W2 = (const float*)d_in[9];
  const float* b2 = (const float*)d_in[10];
  float* out = (float*)d_out;

  float* ws = (float*)d_ws;
  size_t off = 0;
  float* h   = ws + off; off += (size_t)NR * Hd;
  float* plc = ws + off; off += (size_t)Bb * Cc;
  float* cval = ws + off; off += (size_t)Bb * (CH_N * KT);
  int* cidx  = (int*)(ws + off); off += (size_t)Bb * (CH_N * KT);
  int* counts = (int*)(ws + off); off += Nn;
  int* fill   = (int*)(ws + off); off += Nn;
  int* rptr   = (int*)(ws + off); off += Nn + 4;
  int* ccol   = (int*)(ws + off); off += En;
  float* cwt  = ws + off; off += En;
  unsigned short* anb = (unsigned short*)(ws + off); off += (size_t)Bb * Hd / 2;
  unsigned short* hb  = (unsigned short*)(ws + off); off += (size_t)NR * Hd / 2;
  unsigned short* x0b = (unsigned short*)(ws + off); off += (size_t)NR * Hd / 2;
  unsigned short* pb  = (unsigned short*)(ws + off); off += (size_t)NR * Hd / 2;
  unsigned short* W1p = (unsigned short*)(ws + off); off += 65536 / 2;
  unsigned short* Wcp = (unsigned short*)(ws + off); off += 294912 / 2;

  k_pack_w1<<<256, 256, 0, stream>>>(W1, W1p);
  k_pack_wc<<<1152, 256, 0, stream>>>(cw1, cw2, Wcp);
  k_in<<<NR / 64, 256, 0, stream>>>(x, W1p, b1, h, hb, x0b);
  hipMemsetAsync(counts, 0, (size_t)2 * Nn * sizeof(int), stream);
  k_hist<<<(En + 255) / 256, 256, 0, stream>>>(erow, counts);
  k_scan<<<1, 1024, 0, stream>>>(counts, rptr);
  k_scatter<<<(En + 255) / 256, 256, 0, stream>>>(erow, ecol, ew, rptr, fill, ccol, cwt);
  for (int l = 0; l < Ll; ++l) {
    const float beta = logf(1.0f / (float)(l + 1) + 1.0f);
    k_spmm<<<(Nn * 64 + 255) / 256, 256, 0, stream>>>(rptr, ccol, cwt, hb, pb);
    k_layer<<<NR / 64, 256, 0, stream>>>(pb, x0b, Wcp + (size_t)l * 32768, h, hb, beta);
  }
  k_head<<<(Bb * 64) / 256, 256, 0, stream>>>(h, W2, b2, anb, plc, out + (size_t)Bb * Cc);
  k_simtopk<<<((Bb + 63) / 64) * CH_N, 256, 0, stream>>>(anb, cval, cidx);
  k_final<<<(Bb + 255) / 256, 256, 0, stream>>>(cval, cidx, y, plc, out);
}